// Round 12
// baseline (1013.634 us; speedup 1.0000x reference)
//
#include <hip/hip_runtime.h>
#include <hip/hip_bf16.h>

#define N_ATOMS 131072
#define N_EDGES 524288
#define N_MOLS  2048
#define DD      128   // n_atom_basis
#define FF      128   // n_filters
#define GG      50    // n_gaussians
#define TT      3

typedef __hip_bfloat16 bf16;
typedef __attribute__((ext_vector_type(8))) short short8;
typedef __attribute__((ext_vector_type(4))) float floatx4;

__device__ __forceinline__ float b2f(bf16 v) { return __bfloat162float(v); }
__device__ __forceinline__ bf16  f2b(float v) { return __float2bfloat16(v); }

// fast RNE float->bf16 (exact RNE for finite values)
__device__ __forceinline__ unsigned short f2bu(float f) {
    unsigned u = __float_as_uint(f);
    u += 0x7fff + ((u >> 16) & 1);
    return (unsigned short)(u >> 16);
}
__device__ __forceinline__ bf16 f2b_fast(float f) {
    union { unsigned short u; bf16 b; } c; c.u = f2bu(f); return c.b;
}
__device__ __forceinline__ unsigned int pk2(float lo, float hi) {
    return ((unsigned)f2bu(hi) << 16) | f2bu(lo);
}

// unpack two bf16 (packed in a uint) to float2
__device__ __forceinline__ float2 up2(unsigned int u) {
    float2 f;
    f.x = __uint_as_float(u << 16);
    f.y = __uint_as_float(u & 0xffff0000u);
    return f;
}

// shifted softplus via HW transcendentals
__device__ __forceinline__ float sspf(float x) {
    float e = __expf(-fabsf(x));
    return fmaxf(x, 0.f) + __logf(1.f + e) - 0.69314718056f;
}

__device__ __forceinline__ void fma8(float* ac, uint4 wv, uint4 hv) {
    float2 w0 = up2(wv.x), h0 = up2(hv.x);
    float2 w1 = up2(wv.y), h1 = up2(hv.y);
    float2 w2 = up2(wv.z), h2 = up2(hv.z);
    float2 w3 = up2(wv.w), h3 = up2(hv.w);
    ac[0] = fmaf(w0.x, h0.x, ac[0]); ac[1] = fmaf(w0.y, h0.y, ac[1]);
    ac[2] = fmaf(w1.x, h1.x, ac[2]); ac[3] = fmaf(w1.y, h1.y, ac[3]);
    ac[4] = fmaf(w2.x, h2.x, ac[4]); ac[5] = fmaf(w2.y, h2.y, ac[5]);
    ac[6] = fmaf(w3.x, h3.x, ac[6]); ac[7] = fmaf(w3.y, h3.y, ac[7]);
}

// ---------------------------------------------------------------------------
// MFMA helpers (layouts verified, learn_hip m89).
// ---------------------------------------------------------------------------
template <int NCT>
__device__ __forceinline__ void mfma_half(const bf16* A, const bf16* B,
                                          floatx4 (&acc)[2][NCT],
                                          int kA, int wave, int q, int ln) {
#pragma unroll
    for (int k0 = 0; k0 < 64; k0 += 32) {
        short8 a0 = *(const short8*)(A + (wave * 32 + ln) * 136 + kA + k0 + q * 8);
        short8 a1 = *(const short8*)(A + (wave * 32 + 16 + ln) * 136 + kA + k0 + q * 8);
#pragma unroll
        for (int ct = 0; ct < NCT; ct++) {
            short8 b = *(const short8*)(B + (ct * 16 + ln) * 72 + k0 + q * 8);
            acc[0][ct] = __builtin_amdgcn_mfma_f32_16x16x32_bf16(a0, b, acc[0][ct], 0, 0, 0);
            acc[1][ct] = __builtin_amdgcn_mfma_f32_16x16x32_bf16(a1, b, acc[1][ct], 0, 0, 0);
        }
    }
}

template <int NCT>
__device__ __forceinline__ void mfma_halfo(const bf16* A, const bf16* B,
                                           floatx4 (&acc)[2][8], int ctBase,
                                           int kA, int wave, int q, int ln) {
#pragma unroll
    for (int k0 = 0; k0 < 64; k0 += 32) {
        short8 a0 = *(const short8*)(A + (wave * 32 + ln) * 136 + kA + k0 + q * 8);
        short8 a1 = *(const short8*)(A + (wave * 32 + 16 + ln) * 136 + kA + k0 + q * 8);
#pragma unroll
        for (int ct = 0; ct < NCT; ct++) {
            short8 b = *(const short8*)(B + (ct * 16 + ln) * 72 + k0 + q * 8);
            acc[0][ctBase + ct] = __builtin_amdgcn_mfma_f32_16x16x32_bf16(a0, b, acc[0][ctBase + ct], 0, 0, 0);
            acc[1][ctBase + ct] = __builtin_amdgcn_mfma_f32_16x16x32_bf16(a1, b, acc[1][ctBase + ct], 0, 0, 0);
        }
    }
}

template <int NCT>
__device__ __forceinline__ void mfma64(const bf16* A, const bf16* B,
                                       floatx4 (&acc)[NCT],
                                       int kA, int wave, int q, int ln) {
#pragma unroll
    for (int k0 = 0; k0 < 64; k0 += 32) {
        short8 a = *(const short8*)(A + (wave * 16 + ln) * 136 + kA + k0 + q * 8);
#pragma unroll
        for (int ct = 0; ct < NCT; ct++) {
            short8 b = *(const short8*)(B + (ct * 16 + ln) * 72 + k0 + q * 8);
            acc[ct] = __builtin_amdgcn_mfma_f32_16x16x32_bf16(a, b, acc[ct], 0, 0, 0);
        }
    }
}

__device__ __forceinline__ void stage_b(bf16* B, const bf16* WT, int k0,
                                        int nrows, int ldk, int tid) {
    for (int i = tid; i < nrows * 8; i += 256) {
        int n = i >> 3, kc = i & 7;
        *(short8*)(B + n * 72 + kc * 8) =
            *(const short8*)(WT + n * ldk + k0 + kc * 8);
    }
}

// ---------------------------------------------------------------------------
// merged init (r=bf16(emb[z])) + weight transpose/convert
__global__ __launch_bounds__(256) void k_initwt(const float* __restrict__ emb,
                                                const int* __restrict__ z,
                                                bf16* __restrict__ rb,
                                                const float* __restrict__ fw1,
                                                const float* __restrict__ fw2,
                                                const float* __restrict__ win,
                                                const float* __restrict__ wout1,
                                                const float* __restrict__ wout2,
                                                const float* __restrict__ wa1,
                                                bf16* __restrict__ fw1T, bf16* __restrict__ fw2T,
                                                bf16* __restrict__ winT, bf16* __restrict__ wout1T,
                                                bf16* __restrict__ wout2T, bf16* __restrict__ wa1T) {
    int bi = blockIdx.x;
    if (bi < N_ATOMS * 16 / 256) {
        int idx = bi * 256 + threadIdx.x;
        int atom = idx >> 4, seg = idx & 15;
        const float* src = emb + (size_t)z[atom] * DD + seg * 8;
        float4 v0 = *(const float4*)(src);
        float4 v1 = *(const float4*)(src + 4);
        uint4 o;
        o.x = pk2(v0.x, v0.y); o.y = pk2(v0.z, v0.w);
        o.z = pk2(v1.x, v1.y); o.w = pk2(v1.z, v1.w);
        *(uint4*)(rb + (size_t)atom * DD + seg * 8) = o;
        return;
    }
    int idx = (bi - N_ATOMS * 16 / 256) * 256 + threadIdx.x;
    if (idx < 3 * 128 * 64) {
        int t = idx / 8192, j = idx % 8192;
        int n = j >> 6, k = j & 63;
        fw1T[idx] = (k < GG) ? f2b(fw1[t * GG * FF + k * FF + n]) : f2b(0.f);
        return;
    }
    idx -= 3 * 128 * 64;
    if (idx < 3 * 16384) { int t = idx / 16384, j = idx % 16384; int n = j >> 7, k = j & 127;
        fw2T[idx] = f2b(fw2[t * 16384 + k * 128 + n]); return; }
    idx -= 3 * 16384;
    if (idx < 3 * 16384) { int t = idx / 16384, j = idx % 16384; int n = j >> 7, k = j & 127;
        winT[idx] = f2b(win[t * 16384 + k * 128 + n]); return; }
    idx -= 3 * 16384;
    if (idx < 3 * 16384) { int t = idx / 16384, j = idx % 16384; int n = j >> 7, k = j & 127;
        wout1T[idx] = f2b(wout1[t * 16384 + k * 128 + n]); return; }
    idx -= 3 * 16384;
    if (idx < 3 * 16384) { int t = idx / 16384, j = idx % 16384; int n = j >> 7, k = j & 127;
        wout2T[idx] = f2b(wout2[t * 16384 + k * 128 + n]); return; }
    idx -= 3 * 16384;
    if (idx < 64 * 128) { int n = idx >> 7, k = idx & 127;
        wa1T[idx] = f2b(wa1[k * 64 + n]); return; }
}

// fallback-only: d/C in ORIGINAL edge order + molE zero
__global__ __launch_bounds__(256) void k_dist(const float* __restrict__ xyz,
                                              const int* __restrict__ a,
                                              float* __restrict__ dArr,
                                              float* __restrict__ cArr,
                                              float* __restrict__ molE) {
    int e = blockIdx.x * 256 + threadIdx.x;
    if (e < N_MOLS) molE[e] = 0.f;
    int A0 = a[2 * e], A1 = a[2 * e + 1];
    float dx = xyz[3 * A0]     - xyz[3 * A1];
    float dy = xyz[3 * A0 + 1] - xyz[3 * A1 + 1];
    float dz = xyz[3 * A0 + 2] - xyz[3 * A1 + 2];
    float d = sqrtf(dx * dx + dy * dy + dz * dz);
    dArr[e] = d;
    cArr[e] = 0.5f * (__cosf(d * 0.6283185307179586f) + 1.f);
}

// ---------------------------------------------------------------------------
// Graph build. Edges renumbered sorted-by-a0; a1 side via CSR. Joint scans.
// ---------------------------------------------------------------------------
__global__ __launch_bounds__(256) void k_zero2(int* __restrict__ pA,
                                               int* __restrict__ p1) {
    int i = blockIdx.x * 256 + threadIdx.x;
    if (i < N_ATOMS) pA[i] = 0;
    else p1[i - N_ATOMS] = 0;
}

__global__ __launch_bounds__(256) void k_count2(const int* __restrict__ a,
                                                int* __restrict__ cntA,
                                                int* __restrict__ cnt1,
                                                float* __restrict__ molE) {
    int e = blockIdx.x * 256 + threadIdx.x;
    if (e < N_MOLS) molE[e] = 0.f;
    atomicAdd(&cntA[a[2 * e]], 1);
    atomicAdd(&cnt1[a[2 * e + 1]], 1);
}

// scan1j: 512 blocks; first 256 -> cursorA/bsumA, next 256 -> cursor1/bsum1
__global__ __launch_bounds__(256) void k_scan1j(const int* __restrict__ cursorA,
                                                const int* __restrict__ cursor1,
                                                int* __restrict__ bsumA,
                                                int* __restrict__ bsum1) {
    __shared__ int red[256];
    int tid = threadIdx.x;
    int arr = blockIdx.x >> 8, b = blockIdx.x & 255;
    const int* counts = arr ? cursor1 : cursorA;
    int* bsum = arr ? bsum1 : bsumA;
    int i0 = b * 512 + tid * 2;
    red[tid] = counts[i0] + counts[i0 + 1];
    __syncthreads();
    for (int off = 128; off > 0; off >>= 1) {
        if (tid < off) red[tid] += red[tid + off];
        __syncthreads();
    }
    if (tid == 0) bsum[b] = red[0];
}

// scan2j: one block handles both partial arrays
__global__ __launch_bounds__(256) void k_scan2j(int* __restrict__ bsumA,
                                                int* __restrict__ bsum1,
                                                int* __restrict__ baseA,
                                                int* __restrict__ ptr1) {
    __shared__ int v[256];
    int tid = threadIdx.x;
    for (int arr = 0; arr < 2; arr++) {
        int* bsum = arr ? bsum1 : bsumA;
        int* ptrN = arr ? ptr1 : baseA;
        v[tid] = bsum[tid];
        __syncthreads();
        if (tid == 0) {
            int acc = 0;
            for (int i = 0; i < 256; i++) { int t = v[i]; v[i] = acc; acc += t; }
            ptrN[N_ATOMS] = acc;
        }
        __syncthreads();
        bsum[tid] = v[tid];
        __syncthreads();
    }
}

// scan3j: per-block exclusive scan + offset; writes ptr and cursor(in-place)
__global__ __launch_bounds__(256) void k_scan3j(int* __restrict__ cursorA,
                                                int* __restrict__ cursor1,
                                                const int* __restrict__ bsumA,
                                                const int* __restrict__ bsum1,
                                                int* __restrict__ baseA,
                                                int* __restrict__ ptr1) {
    __shared__ int red[256];
    int tid = threadIdx.x;
    int arr = blockIdx.x >> 8, b = blockIdx.x & 255;
    int* counts = arr ? cursor1 : cursorA;
    const int* bsum = arr ? bsum1 : bsumA;
    int* ptr = arr ? ptr1 : baseA;
    int i0 = b * 512 + tid * 2;
    int c0 = counts[i0], c1 = counts[i0 + 1];
    int s = c0 + c1;
    red[tid] = s;
    __syncthreads();
    for (int off = 1; off < 256; off <<= 1) {
        int t = (tid >= off) ? red[tid - off] : 0;
        __syncthreads();
        red[tid] += t;
        __syncthreads();
    }
    int base = bsum[b] + red[tid] - s;  // exclusive prefix
    ptr[i0] = base;
    ptr[i0 + 1] = base + c0;
    counts[i0] = base;
    counts[i0 + 1] = base + c0;
}

__global__ __launch_bounds__(256) void k_permA(const float* __restrict__ xyz,
                                               const int* __restrict__ a,
                                               int* __restrict__ cursorA,
                                               int* __restrict__ cursor1,
                                               float* __restrict__ dAp,
                                               float* __restrict__ cAp,
                                               int* __restrict__ a1s,
                                               int* __restrict__ adj1) {
    int e = blockIdx.x * 256 + threadIdx.x;
    int A0 = a[2 * e], A1 = a[2 * e + 1];
    float dx = xyz[3 * A0]     - xyz[3 * A1];
    float dy = xyz[3 * A0 + 1] - xyz[3 * A1 + 1];
    float dz = xyz[3 * A0 + 2] - xyz[3 * A1 + 2];
    float d = sqrtf(dx * dx + dy * dy + dz * dz);
    int newe = atomicAdd(&cursorA[A0], 1);
    dAp[newe] = d;
    cAp[newe] = 0.5f * (__cosf(d * 0.6283185307179586f) + 1.f);
    a1s[newe] = A1;
    int slot = atomicAdd(&cursor1[A1], 1);
    adj1[2 * slot] = newe;
    adj1[2 * slot + 1] = A0;
}

// ---------------------------------------------------------------------------
// MAIN PATH.  k_he (t=0 only): 128-row tiles, 1:4 h:edge interleave.
// k_e (t=1,2): edge-only. Gather fuses the NEXT iteration's h-GEMM.
// ---------------------------------------------------------------------------
struct SmemHE {
    bf16 A[128][136];
    bf16 B[64][72];
    float dS[128], cS[128], b1S[128], b2S[128];
};

__device__ __forceinline__ void h_part128(SmemHE& sm, int blk,
                                          const bf16* __restrict__ rb,
                                          const bf16* __restrict__ winT_t,
                                          bf16* __restrict__ h) {
    int tid = threadIdx.x, n0 = blk * 128;
    for (int i = tid; i < 128 * 16; i += 256) {
        int row = i >> 4, seg = i & 15;
        *(uint4*)(&sm.A[row][seg * 8]) =
            *(const uint4*)(rb + (size_t)(n0 + row) * DD + seg * 8);
    }
    stage_b(&sm.B[0][0], winT_t, 0, 64, 128, tid);
    __syncthreads();
    int wave = tid >> 6, lane = tid & 63, q = lane >> 4, ln = lane & 15;
    floatx4 acc[2][8];
#pragma unroll
    for (int i = 0; i < 2; i++)
#pragma unroll
        for (int j = 0; j < 8; j++) acc[i][j] = (floatx4){0.f, 0.f, 0.f, 0.f};
    mfma_halfo<4>(&sm.A[0][0], &sm.B[0][0], acc, 0, 0, wave, q, ln);
    __syncthreads();
    stage_b(&sm.B[0][0], winT_t + 64 * 128, 0, 64, 128, tid);
    __syncthreads();
    mfma_halfo<4>(&sm.A[0][0], &sm.B[0][0], acc, 4, 0, wave, q, ln);
    __syncthreads();
    stage_b(&sm.B[0][0], winT_t, 64, 64, 128, tid);
    __syncthreads();
    mfma_halfo<4>(&sm.A[0][0], &sm.B[0][0], acc, 0, 64, wave, q, ln);
    __syncthreads();
    stage_b(&sm.B[0][0], winT_t + 64 * 128, 64, 64, 128, tid);
    __syncthreads();
    mfma_halfo<4>(&sm.A[0][0], &sm.B[0][0], acc, 4, 64, wave, q, ln);
#pragma unroll
    for (int rt = 0; rt < 2; rt++)
#pragma unroll
        for (int cc = 0; cc < 8; cc++)
#pragma unroll
            for (int rg = 0; rg < 4; rg++) {
                int row = wave * 32 + rt * 16 + q * 4 + rg;
                int col = (cc >> 2) * 64 + (cc & 3) * 16 + ln;
                sm.A[row][col] = f2b_fast(acc[rt][cc][rg]);
            }
    __syncthreads();
    for (int i = tid; i < 128 * 16; i += 256) {
        int row = i >> 4, seg = i & 15;
        *(uint4*)(h + (size_t)(n0 + row) * FF + seg * 8) =
            *(const uint4*)(&sm.A[row][seg * 8]);
    }
}

__device__ __forceinline__ void edge_part128(SmemHE& sm, int blk,
                                             const float* __restrict__ dAp,
                                             const float* __restrict__ cAp,
                                             const bf16* __restrict__ fw1T_t,
                                             const float* __restrict__ fb1_t,
                                             const bf16* __restrict__ fw2T_t,
                                             const float* __restrict__ fb2_t,
                                             bf16* __restrict__ Wt) {
    int tid = threadIdx.x, e0 = blk * 128;
    if (tid < 128) {
        sm.dS[tid] = dAp[e0 + tid];
        sm.cS[tid] = cAp[e0 + tid];
        sm.b1S[tid] = fb1_t[tid];
        sm.b2S[tid] = fb2_t[tid];
    }
    stage_b(&sm.B[0][0], fw1T_t, 0, 64, 64, tid);
    __syncthreads();
    const float width = 5.0f / 49.0f;
    const float coeff = -0.5f / (width * width);
    for (int idx = tid; idx < 128 * 32; idx += 256) {
        int i = idx >> 5, kp = (idx & 31) * 2;
        float d = sm.dS[i];
        float t0 = d - (float)kp * width;
        float t1 = d - (float)(kp + 1) * width;
        float v0 = (kp < GG)     ? __expf(coeff * t0 * t0) : 0.f;
        float v1 = (kp + 1 < GG) ? __expf(coeff * t1 * t1) : 0.f;
        *(unsigned int*)(&sm.A[i][kp]) = pk2(v0, v1);
    }
    __syncthreads();
    int wave = tid >> 6, lane = tid & 63, q = lane >> 4, ln = lane & 15;
    floatx4 acc[2][8];
#pragma unroll
    for (int i = 0; i < 2; i++)
#pragma unroll
        for (int j = 0; j < 8; j++) acc[i][j] = (floatx4){0.f, 0.f, 0.f, 0.f};
    // GEMM1: g(K=64) @ fw1 -> 2 n-chunks
    mfma_halfo<4>(&sm.A[0][0], &sm.B[0][0], acc, 0, 0, wave, q, ln);
    __syncthreads();
    stage_b(&sm.B[0][0], fw1T_t + 64 * 64, 0, 64, 64, tid);
    __syncthreads();
    mfma_halfo<4>(&sm.A[0][0], &sm.B[0][0], acc, 4, 0, wave, q, ln);
    // u = ssp(.+b1) -> A (own-wave rows)
#pragma unroll
    for (int rt = 0; rt < 2; rt++)
#pragma unroll
        for (int cc = 0; cc < 8; cc++)
#pragma unroll
            for (int rg = 0; rg < 4; rg++) {
                int row = wave * 32 + rt * 16 + q * 4 + rg;
                int col = (cc >> 2) * 64 + (cc & 3) * 16 + ln;
                sm.A[row][col] = f2b_fast(sspf(acc[rt][cc][rg] + sm.b1S[col]));
            }
    __syncthreads();
    // GEMM2: u(K=128) @ fw2 -> 4 (n,k) chunks
    stage_b(&sm.B[0][0], fw2T_t, 0, 64, 128, tid);
    __syncthreads();
#pragma unroll
    for (int i = 0; i < 2; i++)
#pragma unroll
        for (int j = 0; j < 8; j++) acc[i][j] = (floatx4){0.f, 0.f, 0.f, 0.f};
    mfma_halfo<4>(&sm.A[0][0], &sm.B[0][0], acc, 0, 0, wave, q, ln);
    __syncthreads();
    stage_b(&sm.B[0][0], fw2T_t + 64 * 128, 0, 64, 128, tid);
    __syncthreads();
    mfma_halfo<4>(&sm.A[0][0], &sm.B[0][0], acc, 4, 0, wave, q, ln);
    __syncthreads();
    stage_b(&sm.B[0][0], fw2T_t, 64, 64, 128, tid);
    __syncthreads();
    mfma_halfo<4>(&sm.A[0][0], &sm.B[0][0], acc, 0, 64, wave, q, ln);
    __syncthreads();
    stage_b(&sm.B[0][0], fw2T_t + 64 * 128, 64, 64, 128, tid);
    __syncthreads();
    mfma_halfo<4>(&sm.A[0][0], &sm.B[0][0], acc, 4, 64, wave, q, ln);
#pragma unroll
    for (int rt = 0; rt < 2; rt++)
#pragma unroll
        for (int cc = 0; cc < 8; cc++)
#pragma unroll
            for (int rg = 0; rg < 4; rg++) {
                int row = wave * 32 + rt * 16 + q * 4 + rg;
                int col = (cc >> 2) * 64 + (cc & 3) * 16 + ln;
                sm.A[row][col] = f2b_fast((acc[rt][cc][rg] + sm.b2S[col]) * sm.cS[row]);
            }
    __syncthreads();
    for (int i = tid; i < 128 * 16; i += 256) {
        int row = i >> 4, seg = i & 15;
        *(uint4*)(Wt + (size_t)(e0 + row) * FF + seg * 8) =
            *(const uint4*)(&sm.A[row][seg * 8]);
    }
}

// t=0 only: merged h + edge-filter, 1:4 interleave
__global__ __launch_bounds__(256, 3) void k_he(const bf16* __restrict__ rb,
                                               const bf16* __restrict__ winT_t,
                                               bf16* __restrict__ h,
                                               const float* __restrict__ dAp,
                                               const float* __restrict__ cAp,
                                               const bf16* __restrict__ fw1T_t,
                                               const float* __restrict__ fb1_t,
                                               const bf16* __restrict__ fw2T_t,
                                               const float* __restrict__ fb2_t,
                                               bf16* __restrict__ Wt) {
    __shared__ SmemHE sm;
    int bi = blockIdx.x;
    if (bi % 5 == 0)
        h_part128(sm, bi / 5, rb, winT_t, h);
    else
        edge_part128(sm, bi - bi / 5 - 1, dAp, cAp, fw1T_t, fb1_t, fw2T_t, fb2_t, Wt);
}

// t=1,2: edge-only (h was produced by the previous gather)
__global__ __launch_bounds__(256, 3) void k_e(const float* __restrict__ dAp,
                                              const float* __restrict__ cAp,
                                              const bf16* __restrict__ fw1T_t,
                                              const float* __restrict__ fb1_t,
                                              const bf16* __restrict__ fw2T_t,
                                              const float* __restrict__ fb2_t,
                                              bf16* __restrict__ Wt) {
    __shared__ SmemHE sm;
    edge_part128(sm, blockIdx.x, dAp, cAp, fw1T_t, fb1_t, fw2T_t, fb2_t, Wt);
}

// gather + node MLP + rb update + (fused) NEXT-t h-GEMM (winT_next != null)
__global__ __launch_bounds__(256, 5) void k_gather_node64(const int* __restrict__ baseA,
                                                          const int* __restrict__ a1s,
                                                          const int* __restrict__ ptr1,
                                                          const int* __restrict__ adj1,
                                                          const bf16* __restrict__ Wt,
                                                          const bf16* __restrict__ h,
                                                          const bf16* __restrict__ wout1T_t,
                                                          const float* __restrict__ bo1_t,
                                                          const bf16* __restrict__ wout2T_t,
                                                          const float* __restrict__ bo2_t,
                                                          bf16* __restrict__ rb,
                                                          const bf16* __restrict__ winT_next,
                                                          bf16* __restrict__ hout) {
    __shared__ __align__(16) bf16 A[64][136];
    __shared__ __align__(16) bf16 B[64][72];
    __shared__ float b1S[128], b2S[128];
    int tid = threadIdx.x, n0 = blockIdx.x * 64;
    if (tid < 128) { b1S[tid] = bo1_t[tid]; b2S[tid] = bo2_t[tid]; }
    stage_b(&B[0][0], wout1T_t, 0, 64, 128, tid);  // overlap with gather
    int wave = tid >> 6, lane = tid & 63;
    int seg = lane & 15;   // cols [8*seg, 8*seg+8)
    int rg  = lane >> 4;   // slot-in-group 0..3
    for (int k = 0; k < 16; k += 2) {
        int rowA = wave * 16 + k;
        int atomA = n0 + rowA;
        int2 b01 = *(const int2*)(baseA + atomA);
        int b2v = baseA[atomA + 2];
        int2 p01 = *(const int2*)(ptr1 + atomA);
        int p2v = ptr1[atomA + 2];
        int sA0 = b01.x + rg, eA0v = b01.y;
        int sB0 = b01.y + rg, eB0v = b2v;
        int sA1 = p01.x + rg, eA1v = p01.y;
        int sB1 = p01.y + rg, eB1v = p2v;
        int oA = (sA0 < eA0v) ? a1s[sA0] : 0;
        int oB = (sB0 < eB0v) ? a1s[sB0] : 0;
        int2 eoA = (sA1 < eA1v) ? *(const int2*)(adj1 + 2 * sA1) : make_int2(0, 0);
        int2 eoB = (sB1 < eB1v) ? *(const int2*)(adj1 + 2 * sB1) : make_int2(0, 0);
        float acA[8], acB[8];
#pragma unroll
        for (int j = 0; j < 8; j++) { acA[j] = 0.f; acB[j] = 0.f; }
        while ((sA0 < eA0v) | (sA1 < eA1v) | (sB0 < eB0v) | (sB1 < eB1v)) {
            bool pA0 = sA0 < eA0v, pA1 = sA1 < eA1v;
            bool pB0 = sB0 < eB0v, pB1 = sB1 < eB1v;
            uint4 wvA0, hvA0, wvA1, hvA1, wvB0, hvB0, wvB1, hvB1;
            if (pA0) {
                wvA0 = *(const uint4*)(Wt + (size_t)sA0 * FF + seg * 8);
                hvA0 = *(const uint4*)(h + (size_t)oA * FF + seg * 8);
            }
            if (pA1) {
                wvA1 = *(const uint4*)(Wt + (size_t)eoA.x * FF + seg * 8);
                hvA1 = *(const uint4*)(h + (size_t)eoA.y * FF + seg * 8);
            }
            if (pB0) {
                wvB0 = *(const uint4*)(Wt + (size_t)sB0 * FF + seg * 8);
                hvB0 = *(const uint4*)(h + (size_t)oB * FF + seg * 8);
            }
            if (pB1) {
                wvB1 = *(const uint4*)(Wt + (size_t)eoB.x * FF + seg * 8);
                hvB1 = *(const uint4*)(h + (size_t)eoB.y * FF + seg * 8);
            }
            int sA0n = sA0 + 4, sA1n = sA1 + 4, sB0n = sB0 + 4, sB1n = sB1 + 4;
            int oAn = (sA0n < eA0v) ? a1s[sA0n] : 0;
            int oBn = (sB0n < eB0v) ? a1s[sB0n] : 0;
            int2 eoAn = (sA1n < eA1v) ? *(const int2*)(adj1 + 2 * sA1n) : make_int2(0, 0);
            int2 eoBn = (sB1n < eB1v) ? *(const int2*)(adj1 + 2 * sB1n) : make_int2(0, 0);
            if (pA0) fma8(acA, wvA0, hvA0);
            if (pA1) fma8(acA, wvA1, hvA1);
            if (pB0) fma8(acB, wvB0, hvB0);
            if (pB1) fma8(acB, wvB1, hvB1);
            sA0 = sA0n; sA1 = sA1n; sB0 = sB0n; sB1 = sB1n;
            oA = oAn; oB = oBn; eoA = eoAn; eoB = eoBn;
        }
#pragma unroll
        for (int j = 0; j < 8; j++) {
            float vA = acA[j], vB = acB[j];
            vA += __shfl_down(vA, 32); vB += __shfl_down(vB, 32);
            vA += __shfl_down(vA, 16); vB += __shfl_down(vB, 16);
            acA[j] = vA; acB[j] = vB;
        }
        if (rg == 0) {
            uint4 oU;
            oU.x = pk2(acA[0], acA[1]); oU.y = pk2(acA[2], acA[3]);
            oU.z = pk2(acA[4], acA[5]); oU.w = pk2(acA[6], acA[7]);
            *(uint4*)(&A[rowA][seg * 8]) = oU;
            oU.x = pk2(acB[0], acB[1]); oU.y = pk2(acB[2], acB[3]);
            oU.z = pk2(acB[4], acB[5]); oU.w = pk2(acB[6], acB[7]);
            *(uint4*)(&A[rowA + 1][seg * 8]) = oU;
        }
    }
    __syncthreads();
    int q = lane >> 4, ln = lane & 15;
    floatx4 acc[8];
#pragma unroll
    for (int j = 0; j < 8; j++) acc[j] = (floatx4){0.f, 0.f, 0.f, 0.f};
    mfma64<4>(&A[0][0], &B[0][0], *(floatx4(*)[4])(&acc[0]), 0, wave, q, ln);
    __syncthreads();
    stage_b(&B[0][0], wout1T_t + 64 * 128, 0, 64, 128, tid);
    __syncthreads();
    mfma64<4>(&A[0][0], &B[0][0], *(floatx4(*)[4])(&acc[4]), 0, wave, q, ln);
    __syncthreads();
    stage_b(&B[0][0], wout1T_t, 64, 64, 128, tid);
    __syncthreads();
    mfma64<4>(&A[0][0], &B[0][0], *(floatx4(*)[4])(&acc[0]), 64, wave, q, ln);
    __syncthreads();
    stage_b(&B[0][0], wout1T_t + 64 * 128, 64, 64, 128, tid);
    __syncthreads();
    mfma64<4>(&A[0][0], &B[0][0], *(floatx4(*)[4])(&acc[4]), 64, wave, q, ln);
#pragma unroll
    for (int cc = 0; cc < 8; cc++)
#pragma unroll
        for (int rgi = 0; rgi < 4; rgi++) {
            int row = wave * 16 + q * 4 + rgi;
            int col = (cc >> 2) * 64 + (cc & 3) * 16 + ln;
            A[row][col] = f2b_fast(sspf(acc[cc][rgi] + b1S[col]));
        }
    __syncthreads();
    stage_b(&B[0][0], wout2T_t, 0, 64, 128, tid);
    __syncthreads();
#pragma unroll
    for (int j = 0; j < 8; j++) acc[j] = (floatx4){0.f, 0.f, 0.f, 0.f};
    mfma64<4>(&A[0][0], &B[0][0], *(floatx4(*)[4])(&acc[0]), 0, wave, q, ln);
    __syncthreads();
    stage_b(&B[0][0], wout2T_t + 64 * 128, 0, 64, 128, tid);
    __syncthreads();
    mfma64<4>(&A[0][0], &B[0][0], *(floatx4(*)[4])(&acc[4]), 0, wave, q, ln);
    __syncthreads();
    stage_b(&B[0][0], wout2T_t, 64, 64, 128, tid);
    __syncthreads();
    mfma64<4>(&A[0][0], &B[0][0], *(floatx4(*)[4])(&acc[0]), 64, wave, q, ln);
    __syncthreads();
    stage_b(&B[0][0], wout2T_t + 64 * 128, 64, 64, 128, tid);
    __syncthreads();
    mfma64<4>(&A[0][0], &B[0][0], *(floatx4(*)[4])(&acc[4]), 64, wave, q, ln);
    // rb update; stash rb_new (bf16) into A for the fused h-GEMM (own rows only)
    bool do_h = (winT_next != nullptr);
#pragma unroll
    for (int cc = 0; cc < 8; cc++)
#pragma unroll
        for (int rgi = 0; rgi < 4; rgi++) {
            int row = wave * 16 + q * 4 + rgi;
            int col = (cc >> 2) * 64 + (cc & 3) * 16 + ln;
            size_t off = (size_t)(n0 + row) * DD + col;
            bf16 bv = f2b_fast(b2f(rb[off]) + acc[cc][rgi] + b2S[col]);
            rb[off] = bv;
            if (do_h) A[row][col] = bv;
        }
    if (!do_h) return;
    // fused h(t+1) = bf16(rb_new) @ win(t+1)
    __syncthreads();
    stage_b(&B[0][0], winT_next, 0, 64, 128, tid);
    __syncthreads();
#pragma unroll
    for (int j = 0; j < 8; j++) acc[j] = (floatx4){0.f, 0.f, 0.f, 0.f};
    mfma64<4>(&A[0][0], &B[0][0], *(floatx4(*)[4])(&acc[0]), 0, wave, q, ln);
    __syncthreads();
    stage_b(&B[0][0], winT_next + 64 * 128, 0, 64, 128, tid);
    __syncthreads();
    mfma64<4>(&A[0][0], &B[0][0], *(floatx4(*)[4])(&acc[4]), 0, wave, q, ln);
    __syncthreads();
    stage_b(&B[0][0], winT_next, 64, 64, 128, tid);
    __syncthreads();
    mfma64<4>(&A[0][0], &B[0][0], *(floatx4(*)[4])(&acc[0]), 64, wave, q, ln);
    __syncthreads();
    stage_b(&B[0][0], winT_next + 64 * 128, 64, 64, 128, tid);
    __syncthreads();
    mfma64<4>(&A[0][0], &B[0][0], *(floatx4(*)[4])(&acc[4]), 64, wave, q, ln);
#pragma unroll
    for (int cc = 0; cc < 8; cc++)
#pragma unroll
        for (int rgi = 0; rgi < 4; rgi++) {
            int row = wave * 16 + q * 4 + rgi;
            int col = (cc >> 2) * 64 + (cc & 3) * 16 + ln;
            A[row][col] = f2b_fast(acc[cc][rgi]);
        }
    __syncthreads();
    for (int i = tid; i < 64 * 16; i += 256) {
        int row = i >> 4, sg = i & 15;
        *(uint4*)(hout + (size_t)(n0 + row) * FF + sg * 8) =
            *(const uint4*)(&A[row][sg * 8]);
    }
}

// ---------------------------------------------------------------------------
// FALLBACK (verified structure, bf16 r)
// ---------------------------------------------------------------------------
__global__ __launch_bounds__(256) void k_h(const bf16* __restrict__ rb,
                                           const bf16* __restrict__ winT_t,
                                           bf16* __restrict__ h,
                                           float* __restrict__ y) {
    __shared__ __align__(16) bf16 A[128][136];
    __shared__ __align__(16) bf16 B[128][72];
    int tid = threadIdx.x, n0 = blockIdx.x * 128;
    for (int i = tid; i < 128 * 16; i += 256) {
        int row = i >> 4, seg = i & 15;
        *(uint4*)(&A[row][seg * 8]) =
            *(const uint4*)(rb + (size_t)(n0 + row) * DD + seg * 8);
        *(float4*)(y + (size_t)(n0 + row) * FF + seg * 8) = (float4){0.f, 0.f, 0.f, 0.f};
        *(float4*)(y + (size_t)(n0 + row) * FF + seg * 8 + 4) = (float4){0.f, 0.f, 0.f, 0.f};
    }
    stage_b(&B[0][0], winT_t, 0, 128, 128, tid);
    __syncthreads();
    int wave = tid >> 6, lane = tid & 63, q = lane >> 4, ln = lane & 15;
    floatx4 acc[2][8];
#pragma unroll
    for (int i = 0; i < 2; i++)
#pragma unroll
        for (int j = 0; j < 8; j++) acc[i][j] = (floatx4){0.f, 0.f, 0.f, 0.f};
    mfma_half<8>(&A[0][0], &B[0][0], acc, 0, wave, q, ln);
    __syncthreads();
    stage_b(&B[0][0], winT_t, 64, 128, 128, tid);
    __syncthreads();
    mfma_half<8>(&A[0][0], &B[0][0], acc, 64, wave, q, ln);
#pragma unroll
    for (int rt = 0; rt < 2; rt++)
#pragma unroll
        for (int ct = 0; ct < 8; ct++)
#pragma unroll
            for (int rg = 0; rg < 4; rg++) {
                int row = wave * 32 + rt * 16 + q * 4 + rg, col = ct * 16 + ln;
                h[(size_t)(n0 + row) * FF + col] = f2b(acc[rt][ct][rg]);
            }
}

__global__ __launch_bounds__(256) void k_edge(const float* __restrict__ dArr,
                                              const float* __restrict__ cArr,
                                              const int* __restrict__ a,
                                              const bf16* __restrict__ fw1T_t,
                                              const float* __restrict__ fb1_t,
                                              const bf16* __restrict__ fw2T_t,
                                              const float* __restrict__ fb2_t,
                                              const bf16* __restrict__ h,
                                              float* __restrict__ y) {
    __shared__ __align__(16) bf16 A[128][136];
    __shared__ __align__(16) bf16 B[128][72];
    __shared__ float dS[128], cS[128], b1S[128], b2S[128];
    __shared__ int a0S[128], a1S[128];
    int tid = threadIdx.x, e0 = blockIdx.x * 128;
    if (tid < 128) {
        int e = e0 + tid;
        dS[tid] = dArr[e]; cS[tid] = cArr[e];
        a0S[tid] = a[2 * e]; a1S[tid] = a[2 * e + 1];
        b1S[tid] = fb1_t[tid]; b2S[tid] = fb2_t[tid];
    }
    stage_b(&B[0][0], fw1T_t, 0, 128, 64, tid);
    __syncthreads();
    const float width = 5.0f / 49.0f;
    const float coeff = -0.5f / (width * width);
    for (int idx = tid; idx < 128 * 64; idx += 256) {
        int i = idx >> 6, k = idx & 63;
        float v = 0.f;
        if (k < GG) { float t = dS[i] - (float)k * width; v = __expf(coeff * t * t); }
        A[i][k] = f2b(v);
    }
    __syncthreads();
    int wave = tid >> 6, lane = tid & 63, q = lane >> 4, ln = lane & 15;
    floatx4 acc[2][8];
#pragma unroll
    for (int i = 0; i < 2; i++)
#pragma unroll
        for (int j = 0; j < 8; j++) acc[i][j] = (floatx4){0.f, 0.f, 0.f, 0.f};
    mfma_half<8>(&A[0][0], &B[0][0], acc, 0, wave, q, ln);
#pragma unroll
    for (int rt = 0; rt < 2; rt++)
#pragma unroll
        for (int ct = 0; ct < 8; ct++)
#pragma unroll
            for (int rg = 0; rg < 4; rg++) {
                int row = wave * 32 + rt * 16 + q * 4 + rg, col = ct * 16 + ln;
                A[row][col] = f2b(sspf(acc[rt][ct][rg] + b1S[col]));
            }
    __syncthreads();
    stage_b(&B[0][0], fw2T_t, 0, 128, 128, tid);
    __syncthreads();
#pragma unroll
    for (int i = 0; i < 2; i++)
#pragma unroll
        for (int j = 0; j < 8; j++) acc[i][j] = (floatx4){0.f, 0.f, 0.f, 0.f};
    mfma_half<8>(&A[0][0], &B[0][0], acc, 0, wave, q, ln);
    __syncthreads();
    stage_b(&B[0][0], fw2T_t, 64, 128, 128, tid);
    __syncthreads();
    mfma_half<8>(&A[0][0], &B[0][0], acc, 64, wave, q, ln);
#pragma unroll
    for (int rt = 0; rt < 2; rt++)
#pragma unroll
        for (int ct = 0; ct < 8; ct++)
#pragma unroll
            for (int rg = 0; rg < 4; rg++) {
                int row = wave * 32 + rt * 16 + q * 4 + rg, col = ct * 16 + ln;
                float w = (acc[rt][ct][rg] + b2S[col]) * cS[row];
                int A0 = a0S[row], A1 = a1S[row];
                float h0 = b2f(h[A0 * FF + col]);
                float h1 = b2f(h[A1 * FF + col]);
                atomicAdd(&y[A0 * FF + col], h1 * w);
                atomicAdd(&y[A1 * FF + col], h0 * w);
            }
}

__global__ __launch_bounds__(256) void k_node(const float* __restrict__ y,
                                              const bf16* __restrict__ wout1T_t,
                                              const float* __restrict__ bo1_t,
                                              const bf16* __restrict__ wout2T_t,
                                              const float* __restrict__ bo2_t,
                                              bf16* __restrict__ rb) {
    __shared__ __align__(16) bf16 A[128][136];
    __shared__ __align__(16) bf16 B[128][72];
    __shared__ float b1S[128], b2S[128];
    int tid = threadIdx.x, n0 = blockIdx.x * 128;
    if (tid < 128) { b1S[tid] = bo1_t[tid]; b2S[tid] = bo2_t[tid]; }
    for (int idx = tid; idx < 128 * 128; idx += 256) {
        int row = idx >> 7, col = idx & 127;
        A[row][col] = f2b(y[(size_t)(n0 + row) * FF + col]);
    }
    stage_b(&B[0][0], wout1T_t, 0, 128, 128, tid);
    __syncthreads();
    int wave = tid >> 6, lane = tid & 63, q = lane >> 4, ln = lane & 15;
    floatx4 acc[2][8];
#pragma unroll
    for (int i = 0; i < 2; i++)
#pragma unroll
        for (int j = 0; j < 8; j++) acc[i][j] = (floatx4){0.f, 0.f, 0.f, 0.f};
    mfma_half<8>(&A[0][0], &B[0][0], acc, 0, wave, q, ln);
    __syncthreads();
    stage_b(&B[0][0], wout1T_t, 64, 128, 128, tid);
    __syncthreads();
    mfma_half<8>(&A[0][0], &B[0][0], acc, 64, wave, q, ln);
#pragma unroll
    for (int rt = 0; rt < 2; rt++)
#pragma unroll
        for (int ct = 0; ct < 8; ct++)
#pragma unroll
            for (int rg = 0; rg < 4; rg++) {
                int row = wave * 32 + rt * 16 + q * 4 + rg, col = ct * 16 + ln;
                A[row][col] = f2b(sspf(acc[rt][ct][rg] + b1S[col]));
            }
    __syncthreads();
    stage_b(&B[0][0], wout2T_t, 0, 128, 128, tid);
    __syncthreads();
#pragma unroll
    for (int i = 0; i < 2; i++)
#pragma unroll
        for (int j = 0; j < 8; j++) acc[i][j] = (floatx4){0.f, 0.f, 0.f, 0.f};
    mfma_half<8>(&A[0][0], &B[0][0], acc, 0, wave, q, ln);
    __syncthreads();
    stage_b(&B[0][0], wout2T_t, 64, 128, 128, tid);
    __syncthreads();
    mfma_half<8>(&A[0][0], &B[0][0], acc, 64, wave, q, ln);
#pragma unroll
    for (int rt = 0; rt < 2; rt++)
#pragma unroll
        for (int ct = 0; ct < 8; ct++)
#pragma unroll
            for (int rg = 0; rg < 4; rg++) {
                int row = wave * 32 + rt * 16 + q * 4 + rg, col = ct * 16 + ln;
                size_t off = (size_t)(n0 + row) * DD + col;
                rb[off] = f2b_fast(b2f(rb[off]) + acc[rt][ct][rg] + b2S[col]);
            }
}

// ---------------------------------------------------------------------------
__global__ __launch_bounds__(256) void k_head(const bf16* __restrict__ rb,
                                              const bf16* __restrict__ wa1T,
                                              const float* __restrict__ ba1,
                                              const float* __restrict__ wa2,
                                              const float* __restrict__ ba2,
                                              const int* __restrict__ mol,
                                              float* __restrict__ molE) {
    __shared__ __align__(16) bf16 A[128][136];
    __shared__ __align__(16) bf16 B[64][72];
    __shared__ __align__(16) bf16 U[128][72];
    __shared__ float wa2S[64], ba1S[64];
    int tid = threadIdx.x, n0 = blockIdx.x * 128;
    if (tid < 64) { wa2S[tid] = wa2[tid]; ba1S[tid] = ba1[tid]; }
    for (int i = tid; i < 128 * 16; i += 256) {
        int row = i >> 4, seg = i & 15;
        *(uint4*)(&A[row][seg * 8]) =
            *(const uint4*)(rb + (size_t)(n0 + row) * DD + seg * 8);
    }
    stage_b(&B[0][0], wa1T, 0, 64, 128, tid);
    __syncthreads();
    int wave = tid >> 6, lane = tid & 63, q = lane >> 4, ln = lane & 15;
    floatx4 acc[2][4];
#pragma unroll
    for (int i = 0; i < 2; i++)
#pragma unroll
        for (int j = 0; j < 4; j++) acc[i][j] = (floatx4){0.f, 0.f, 0.f, 0.f};
    mfma_half<4>(&A[0][0], &B[0][0], acc, 0, wave, q, ln);
    __syncthreads();
    stage_b(&B[0][0], wa1T, 64, 64, 128, tid);
    __syncthreads();
    mfma_half<4>(&A[0][0], &B[0][0], acc, 64, wave, q, ln);
#pragma unroll
    for (int rt = 0; rt < 2; rt++)
#pragma unroll
        for (int ct = 0; ct < 4; ct++)
#pragma unroll
            for (int rg = 0; rg < 4; rg++) {
                int row = wave * 32 + rt * 16 + q * 4 + rg, col = ct * 16 + ln;
                U[row][col] = f2b_fast(acc[rt][ct][rg] + ba1S[col]);
            }
    __syncthreads();
    if (tid < 128) {
        float s = ba2[0];
#pragma unroll
        for (int j = 0; j < 64; j++) s += sspf(b2f(U[tid][j])) * wa2S[j];
        atomicAdd(&molE[mol[n0 + tid]], s);
    }
}

__global__ __launch_bounds__(256) void k_out(const float* __restrict__ molE,
                                             float* __restrict__ out) {
    int i = blockIdx.x * 256 + threadIdx.x;
    out[i] = molE[i];
}

// ---------------------------------------------------------------------------
extern "C" void kernel_launch(void* const* d_in, const int* in_sizes, int n_in,
                              void* d_out, int out_size, void* d_ws, size_t ws_size,
                              hipStream_t stream) {
    const float* xyz   = (const float*)d_in[0];
    const float* emb   = (const float*)d_in[1];
    const float* fw1   = (const float*)d_in[2];
    const float* fb1   = (const float*)d_in[3];
    const float* fw2   = (const float*)d_in[4];
    const float* fb2   = (const float*)d_in[5];
    const float* win   = (const float*)d_in[6];
    const float* wout1 = (const float*)d_in[7];
    const float* bout1 = (const float*)d_in[8];
    const float* wout2 = (const float*)d_in[9];
    const float* bout2 = (const float*)d_in[10];
    const float* wa1   = (const float*)d_in[11];
    const float* ba1   = (const float*)d_in[12];
    const float* wa2   = (const float*)d_in[13];
    const float* ba2   = (const float*)d_in[14];
    const int*  z     = (const int*)d_in[15];
    const int*  a     = (const int*)d_in[16];
    const int*  mol   = (const int*)d_in[17];

    char* ws = (char*)d_ws;
    bf16*  rb   = (bf16*) ws; ws += (size_t)N_ATOMS * DD * 2;     //  33,554,432
    bf16*  h    = (bf16*) ws; ws += (size_t)N_ATOMS * FF * 2;     //  33,554,432
    float* molE = (float*)ws; ws += (size_t)N_MOLS * 4;
    float* dAp  = (float*)ws; ws += (size_t)N_EDGES * 4;          //   2,097,152
    float* cAp  = (float*)ws; ws += (size_t)N_EDGES * 4;          //   2,097,152
    bf16*  fw1T   = (bf16*)ws; ws += 3 * 128 * 64 * 2;
    bf16*  fw2T   = (bf16*)ws; ws += 3 * 128 * 128 * 2;
    bf16*  winT   = (bf16*)ws; ws += 3 * 128 * 128 * 2;
    bf16*  wout1T = (bf16*)ws; ws += 3 * 128 * 128 * 2;
    bf16*  wout2T = (bf16*)ws; ws += 3 * 128 * 128 * 2;
    bf16*  wa1T   = (bf16*)ws; ws += 64 * 128 * 2;
    char*  csr_base = ws;                                          // fallback y aliases here
    int*   baseA   = (int*)ws; ws += 524320;                      // N_ATOMS+1, padded
    int*   ptr1    = (int*)ws; ws += 524320;
    int*   cursorA = (int*)ws; ws += (size_t)N_ATOMS * 4;
    int*   cursor1 = (int*)ws; ws += (size_t)N_ATOMS * 4;
    int*   a1s     = (int*)ws; ws += (size_t)N_EDGES * 4;         //   2,097,152
    int*   adj1    = (int*)ws; ws += (size_t)2 * N_EDGES * 4;     //   4,194,304
    int*   bsumA   = (int*)ws; ws += 1024;
    int*   bsum1   = (int*)ws; ws += 1024;
    bf16*  Wt      = (bf16*)ws; ws += (size_t)N_EDGES * FF * 2;   // 134,217,728
    size_t need = (size_t)(ws - (char*)d_ws);                     // ~214 MB

    k_initwt<<<N_ATOMS * 16 / 256 + 896, 256, 0, stream>>>(
        emb, z, rb, fw1, fw2, win, wout1, wout2, wa1,
        fw1T, fw2T, winT, wout1T, wout2T, wa1T);

    if (ws_size >= need) {
        k_zero2<<<2 * N_ATOMS / 256, 256, 0, stream>>>(cursorA, cursor1);
        k_count2<<<N_EDGES / 256, 256, 0, stream>>>(a, cursorA, cursor1, molE);
        k_scan1j<<<512, 256, 0, stream>>>(cursorA, cursor1, bsumA, bsum1);
        k_scan2j<<<1, 256, 0, stream>>>(bsumA, bsum1, baseA, ptr1);
        k_scan3j<<<512, 256, 0, stream>>>(cursorA, cursor1, bsumA, bsum1, baseA, ptr1);
        k_permA<<<N_EDGES / 256, 256, 0, stream>>>(xyz, a, cursorA, cursor1,
                                                   dAp, cAp, a1s, adj1);
        for (int t = 0; t < TT; t++) {
            if (t == 0) {
                k_he<<<N_ATOMS / 128 + N_EDGES / 128, 256, 0, stream>>>(
                    rb, winT, h, dAp, cAp,
                    fw1T, fb1, fw2T, fb2, Wt);
            } else {
                k_e<<<N_EDGES / 128, 256, 0, stream>>>(
                    dAp, cAp,
                    fw1T + t * 8192, fb1 + t * FF,
                    fw2T + t * 16384, fb2 + t * FF, Wt);
            }
            const bf16* winN = (t < TT - 1) ? (winT + (t + 1) * 16384) : nullptr;
            k_gather_node64<<<N_ATOMS / 64, 256, 0, stream>>>(
                baseA, a1s, ptr1, adj1, Wt, h,
                wout1T + t * 16384, bout1 + t * DD,
                wout2T + t * 16384, bout2 + t * DD, rb,
                winN, h);
        }
    } else {
        // fallback: verified atomic-scatter path (y aliases CSR region)
        float* y = (float*)csr_base;
        k_dist<<<N_EDGES / 256, 256, 0, stream>>>(xyz, a, dAp, cAp, molE);
        for (int t = 0; t < TT; t++) {
            k_h<<<N_ATOMS / 128, 256, 0, stream>>>(rb, winT + t * 16384, h, y);
            k_edge<<<N_EDGES / 128, 256, 0, stream>>>(dAp, cAp, a,
                                                      fw1T + t * 8192, fb1 + t * FF,
                                                      fw2T + t * 16384, fb2 + t * FF, h, y);
            k_node<<<N_ATOMS / 128, 256, 0, stream>>>(y, wout1T + t * 16384, bout1 + t * DD,
                                                      wout2T + t * 16384, bout2 + t * DD, rb);
        }
    }
    k_head<<<N_ATOMS / 128, 256, 0, stream>>>(rb, wa1T, ba1, wa2, ba2, mol, molE);
    k_out<<<N_MOLS / 256, 256, 0, stream>>>(molE, (float*)d_out);
}

// Round 13
// 957.760 us; speedup vs baseline: 1.0583x; 1.0583x over previous
//
#include <hip/hip_runtime.h>
#include <hip/hip_bf16.h>

#define N_ATOMS 131072
#define N_EDGES 524288
#define N_MOLS  2048
#define DD      128   // n_atom_basis
#define FF      128   // n_filters
#define GG      50    // n_gaussians
#define TT      3

typedef __hip_bfloat16 bf16;
typedef __attribute__((ext_vector_type(8))) short short8;
typedef __attribute__((ext_vector_type(4))) float floatx4;

__device__ __forceinline__ float b2f(bf16 v) { return __bfloat162float(v); }
__device__ __forceinline__ bf16  f2b(float v) { return __float2bfloat16(v); }

// fast RNE float->bf16 (exact RNE for finite values)
__device__ __forceinline__ unsigned short f2bu(float f) {
    unsigned u = __float_as_uint(f);
    u += 0x7fff + ((u >> 16) & 1);
    return (unsigned short)(u >> 16);
}
__device__ __forceinline__ bf16 f2b_fast(float f) {
    union { unsigned short u; bf16 b; } c; c.u = f2bu(f); return c.b;
}
__device__ __forceinline__ unsigned int pk2(float lo, float hi) {
    return ((unsigned)f2bu(hi) << 16) | f2bu(lo);
}

// unpack two bf16 (packed in a uint) to float2
__device__ __forceinline__ float2 up2(unsigned int u) {
    float2 f;
    f.x = __uint_as_float(u << 16);
    f.y = __uint_as_float(u & 0xffff0000u);
    return f;
}

// shifted softplus via HW transcendentals
__device__ __forceinline__ float sspf(float x) {
    float e = __expf(-fabsf(x));
    return fmaxf(x, 0.f) + __logf(1.f + e) - 0.69314718056f;
}

__device__ __forceinline__ void fma8(float* ac, uint4 wv, uint4 hv) {
    float2 w0 = up2(wv.x), h0 = up2(hv.x);
    float2 w1 = up2(wv.y), h1 = up2(hv.y);
    float2 w2 = up2(wv.z), h2 = up2(hv.z);
    float2 w3 = up2(wv.w), h3 = up2(hv.w);
    ac[0] = fmaf(w0.x, h0.x, ac[0]); ac[1] = fmaf(w0.y, h0.y, ac[1]);
    ac[2] = fmaf(w1.x, h1.x, ac[2]); ac[3] = fmaf(w1.y, h1.y, ac[3]);
    ac[4] = fmaf(w2.x, h2.x, ac[4]); ac[5] = fmaf(w2.y, h2.y, ac[5]);
    ac[6] = fmaf(w3.x, h3.x, ac[6]); ac[7] = fmaf(w3.y, h3.y, ac[7]);
}

// ---------------------------------------------------------------------------
// MFMA helpers (layouts verified, learn_hip m89).
// mfma_half: 128-row A, wave owns rows [32w,32w+32) (fallback, 256 thr)
// mfma64: wave owns rows [16w,16w+16)  (works for any wave count)
// ---------------------------------------------------------------------------
template <int NCT>
__device__ __forceinline__ void mfma_half(const bf16* A, const bf16* B,
                                          floatx4 (&acc)[2][NCT],
                                          int kA, int wave, int q, int ln) {
#pragma unroll
    for (int k0 = 0; k0 < 64; k0 += 32) {
        short8 a0 = *(const short8*)(A + (wave * 32 + ln) * 136 + kA + k0 + q * 8);
        short8 a1 = *(const short8*)(A + (wave * 32 + 16 + ln) * 136 + kA + k0 + q * 8);
#pragma unroll
        for (int ct = 0; ct < NCT; ct++) {
            short8 b = *(const short8*)(B + (ct * 16 + ln) * 72 + k0 + q * 8);
            acc[0][ct] = __builtin_amdgcn_mfma_f32_16x16x32_bf16(a0, b, acc[0][ct], 0, 0, 0);
            acc[1][ct] = __builtin_amdgcn_mfma_f32_16x16x32_bf16(a1, b, acc[1][ct], 0, 0, 0);
        }
    }
}

template <int NCT>
__device__ __forceinline__ void mfma64(const bf16* A, const bf16* B,
                                       floatx4 (&acc)[NCT],
                                       int kA, int wave, int q, int ln) {
#pragma unroll
    for (int k0 = 0; k0 < 64; k0 += 32) {
        short8 a = *(const short8*)(A + (wave * 16 + ln) * 136 + kA + k0 + q * 8);
#pragma unroll
        for (int ct = 0; ct < NCT; ct++) {
            short8 b = *(const short8*)(B + (ct * 16 + ln) * 72 + k0 + q * 8);
            acc[ct] = __builtin_amdgcn_mfma_f32_16x16x32_bf16(a, b, acc[ct], 0, 0, 0);
        }
    }
}

__device__ __forceinline__ void stage_b(bf16* B, const bf16* WT, int k0,
                                        int nrows, int ldk, int tid) {
    for (int i = tid; i < nrows * 8; i += 256) {
        int n = i >> 3, kc = i & 7;
        *(short8*)(B + n * 72 + kc * 8) =
            *(const short8*)(WT + n * ldk + k0 + kc * 8);
    }
}

__device__ __forceinline__ void stage_b512(bf16* B, const bf16* WT, int k0,
                                           int nrows, int ldk, int tid) {
    for (int i = tid; i < nrows * 8; i += 512) {
        int n = i >> 3, kc = i & 7;
        *(short8*)(B + n * 72 + kc * 8) =
            *(const short8*)(WT + n * ldk + k0 + kc * 8);
    }
}

// ---------------------------------------------------------------------------
// merged init (r=bf16(emb[z])) + weight transpose/convert
__global__ __launch_bounds__(256) void k_initwt(const float* __restrict__ emb,
                                                const int* __restrict__ z,
                                                bf16* __restrict__ rb,
                                                const float* __restrict__ fw1,
                                                const float* __restrict__ fw2,
                                                const float* __restrict__ win,
                                                const float* __restrict__ wout1,
                                                const float* __restrict__ wout2,
                                                const float* __restrict__ wa1,
                                                bf16* __restrict__ fw1T, bf16* __restrict__ fw2T,
                                                bf16* __restrict__ winT, bf16* __restrict__ wout1T,
                                                bf16* __restrict__ wout2T, bf16* __restrict__ wa1T) {
    int bi = blockIdx.x;
    if (bi < N_ATOMS * 16 / 256) {
        int idx = bi * 256 + threadIdx.x;
        int atom = idx >> 4, seg = idx & 15;
        const float* src = emb + (size_t)z[atom] * DD + seg * 8;
        float4 v0 = *(const float4*)(src);
        float4 v1 = *(const float4*)(src + 4);
        uint4 o;
        o.x = pk2(v0.x, v0.y); o.y = pk2(v0.z, v0.w);
        o.z = pk2(v1.x, v1.y); o.w = pk2(v1.z, v1.w);
        *(uint4*)(rb + (size_t)atom * DD + seg * 8) = o;
        return;
    }
    int idx = (bi - N_ATOMS * 16 / 256) * 256 + threadIdx.x;
    if (idx < 3 * 128 * 64) {
        int t = idx / 8192, j = idx % 8192;
        int n = j >> 6, k = j & 63;
        fw1T[idx] = (k < GG) ? f2b(fw1[t * GG * FF + k * FF + n]) : f2b(0.f);
        return;
    }
    idx -= 3 * 128 * 64;
    if (idx < 3 * 16384) { int t = idx / 16384, j = idx % 16384; int n = j >> 7, k = j & 127;
        fw2T[idx] = f2b(fw2[t * 16384 + k * 128 + n]); return; }
    idx -= 3 * 16384;
    if (idx < 3 * 16384) { int t = idx / 16384, j = idx % 16384; int n = j >> 7, k = j & 127;
        winT[idx] = f2b(win[t * 16384 + k * 128 + n]); return; }
    idx -= 3 * 16384;
    if (idx < 3 * 16384) { int t = idx / 16384, j = idx % 16384; int n = j >> 7, k = j & 127;
        wout1T[idx] = f2b(wout1[t * 16384 + k * 128 + n]); return; }
    idx -= 3 * 16384;
    if (idx < 3 * 16384) { int t = idx / 16384, j = idx % 16384; int n = j >> 7, k = j & 127;
        wout2T[idx] = f2b(wout2[t * 16384 + k * 128 + n]); return; }
    idx -= 3 * 16384;
    if (idx < 64 * 128) { int n = idx >> 7, k = idx & 127;
        wa1T[idx] = f2b(wa1[k * 64 + n]); return; }
}

// fallback-only: d/C in ORIGINAL edge order + molE zero
__global__ __launch_bounds__(256) void k_dist(const float* __restrict__ xyz,
                                              const int* __restrict__ a,
                                              float* __restrict__ dArr,
                                              float* __restrict__ cArr,
                                              float* __restrict__ molE) {
    int e = blockIdx.x * 256 + threadIdx.x;
    if (e < N_MOLS) molE[e] = 0.f;
    int A0 = a[2 * e], A1 = a[2 * e + 1];
    float dx = xyz[3 * A0]     - xyz[3 * A1];
    float dy = xyz[3 * A0 + 1] - xyz[3 * A1 + 1];
    float dz = xyz[3 * A0 + 2] - xyz[3 * A1 + 2];
    float d = sqrtf(dx * dx + dy * dy + dz * dz);
    dArr[e] = d;
    cArr[e] = 0.5f * (__cosf(d * 0.6283185307179586f) + 1.f);
}

// ---------------------------------------------------------------------------
// Graph build. Edges renumbered sorted-by-a0; a1 side via CSR. Joint scans.
// ---------------------------------------------------------------------------
__global__ __launch_bounds__(256) void k_zero2(int* __restrict__ pA,
                                               int* __restrict__ p1) {
    int i = blockIdx.x * 256 + threadIdx.x;
    if (i < N_ATOMS) pA[i] = 0;
    else p1[i - N_ATOMS] = 0;
}

__global__ __launch_bounds__(256) void k_count2(const int* __restrict__ a,
                                                int* __restrict__ cntA,
                                                int* __restrict__ cnt1,
                                                float* __restrict__ molE) {
    int e = blockIdx.x * 256 + threadIdx.x;
    if (e < N_MOLS) molE[e] = 0.f;
    atomicAdd(&cntA[a[2 * e]], 1);
    atomicAdd(&cnt1[a[2 * e + 1]], 1);
}

// scan1j: 512 blocks; first 256 -> cursorA/bsumA, next 256 -> cursor1/bsum1
__global__ __launch_bounds__(256) void k_scan1j(const int* __restrict__ cursorA,
                                                const int* __restrict__ cursor1,
                                                int* __restrict__ bsumA,
                                                int* __restrict__ bsum1) {
    __shared__ int red[256];
    int tid = threadIdx.x;
    int arr = blockIdx.x >> 8, b = blockIdx.x & 255;
    const int* counts = arr ? cursor1 : cursorA;
    int* bsum = arr ? bsum1 : bsumA;
    int i0 = b * 512 + tid * 2;
    red[tid] = counts[i0] + counts[i0 + 1];
    __syncthreads();
    for (int off = 128; off > 0; off >>= 1) {
        if (tid < off) red[tid] += red[tid + off];
        __syncthreads();
    }
    if (tid == 0) bsum[b] = red[0];
}

// scan2j: one block handles both partial arrays
__global__ __launch_bounds__(256) void k_scan2j(int* __restrict__ bsumA,
                                                int* __restrict__ bsum1,
                                                int* __restrict__ baseA,
                                                int* __restrict__ ptr1) {
    __shared__ int v[256];
    int tid = threadIdx.x;
    for (int arr = 0; arr < 2; arr++) {
        int* bsum = arr ? bsum1 : bsumA;
        int* ptrN = arr ? ptr1 : baseA;
        v[tid] = bsum[tid];
        __syncthreads();
        if (tid == 0) {
            int acc = 0;
            for (int i = 0; i < 256; i++) { int t = v[i]; v[i] = acc; acc += t; }
            ptrN[N_ATOMS] = acc;
        }
        __syncthreads();
        bsum[tid] = v[tid];
        __syncthreads();
    }
}

// scan3j: per-block exclusive scan + offset; writes ptr and cursor(in-place)
__global__ __launch_bounds__(256) void k_scan3j(int* __restrict__ cursorA,
                                                int* __restrict__ cursor1,
                                                const int* __restrict__ bsumA,
                                                const int* __restrict__ bsum1,
                                                int* __restrict__ baseA,
                                                int* __restrict__ ptr1) {
    __shared__ int red[256];
    int tid = threadIdx.x;
    int arr = blockIdx.x >> 8, b = blockIdx.x & 255;
    int* counts = arr ? cursor1 : cursorA;
    const int* bsum = arr ? bsum1 : bsumA;
    int* ptr = arr ? ptr1 : baseA;
    int i0 = b * 512 + tid * 2;
    int c0 = counts[i0], c1 = counts[i0 + 1];
    int s = c0 + c1;
    red[tid] = s;
    __syncthreads();
    for (int off = 1; off < 256; off <<= 1) {
        int t = (tid >= off) ? red[tid - off] : 0;
        __syncthreads();
        red[tid] += t;
        __syncthreads();
    }
    int base = bsum[b] + red[tid] - s;  // exclusive prefix
    ptr[i0] = base;
    ptr[i0 + 1] = base + c0;
    counts[i0] = base;
    counts[i0 + 1] = base + c0;
}

__global__ __launch_bounds__(256) void k_permA(const float* __restrict__ xyz,
                                               const int* __restrict__ a,
                                               int* __restrict__ cursorA,
                                               int* __restrict__ cursor1,
                                               float* __restrict__ dAp,
                                               float* __restrict__ cAp,
                                               int* __restrict__ a1s,
                                               int* __restrict__ adj1) {
    int e = blockIdx.x * 256 + threadIdx.x;
    int A0 = a[2 * e], A1 = a[2 * e + 1];
    float dx = xyz[3 * A0]     - xyz[3 * A1];
    float dy = xyz[3 * A0 + 1] - xyz[3 * A1 + 1];
    float dz = xyz[3 * A0 + 2] - xyz[3 * A1 + 2];
    float d = sqrtf(dx * dx + dy * dy + dz * dz);
    int newe = atomicAdd(&cursorA[A0], 1);
    dAp[newe] = d;
    cAp[newe] = 0.5f * (__cosf(d * 0.6283185307179586f) + 1.f);
    a1s[newe] = A1;
    int slot = atomicAdd(&cursor1[A1], 1);
    adj1[2 * slot] = newe;
    adj1[2 * slot + 1] = A0;
}

// ---------------------------------------------------------------------------
// MAIN PATH.  k_he/k_e: 128-row tiles, 512 threads = 8 waves (1 row-tile each)
// -> 3 blocks/CU x 8 waves = 24 waves/CU (was 12) to hide barrier stalls.
// ---------------------------------------------------------------------------
struct SmemHE {
    bf16 A[128][136];
    bf16 B[64][72];
    float dS[128], cS[128], b1S[128], b2S[128];
};

__device__ __forceinline__ void h_part512(SmemHE& sm, int blk,
                                          const bf16* __restrict__ rb,
                                          const bf16* __restrict__ winT_t,
                                          bf16* __restrict__ h) {
    int tid = threadIdx.x, n0 = blk * 128;
    for (int i = tid; i < 128 * 16; i += 512) {
        int row = i >> 4, seg = i & 15;
        *(uint4*)(&sm.A[row][seg * 8]) =
            *(const uint4*)(rb + (size_t)(n0 + row) * DD + seg * 8);
    }
    stage_b512(&sm.B[0][0], winT_t, 0, 64, 128, tid);
    __syncthreads();
    int wave = tid >> 6, lane = tid & 63, q = lane >> 4, ln = lane & 15;
    floatx4 acc[8];
#pragma unroll
    for (int j = 0; j < 8; j++) acc[j] = (floatx4){0.f, 0.f, 0.f, 0.f};
    mfma64<4>(&sm.A[0][0], &sm.B[0][0], *(floatx4(*)[4])(&acc[0]), 0, wave, q, ln);
    __syncthreads();
    stage_b512(&sm.B[0][0], winT_t + 64 * 128, 0, 64, 128, tid);
    __syncthreads();
    mfma64<4>(&sm.A[0][0], &sm.B[0][0], *(floatx4(*)[4])(&acc[4]), 0, wave, q, ln);
    __syncthreads();
    stage_b512(&sm.B[0][0], winT_t, 64, 64, 128, tid);
    __syncthreads();
    mfma64<4>(&sm.A[0][0], &sm.B[0][0], *(floatx4(*)[4])(&acc[0]), 64, wave, q, ln);
    __syncthreads();
    stage_b512(&sm.B[0][0], winT_t + 64 * 128, 64, 64, 128, tid);
    __syncthreads();
    mfma64<4>(&sm.A[0][0], &sm.B[0][0], *(floatx4(*)[4])(&acc[4]), 64, wave, q, ln);
#pragma unroll
    for (int cc = 0; cc < 8; cc++)
#pragma unroll
        for (int rg = 0; rg < 4; rg++) {
            int row = wave * 16 + q * 4 + rg;
            int col = (cc >> 2) * 64 + (cc & 3) * 16 + ln;
            sm.A[row][col] = f2b_fast(acc[cc][rg]);
        }
    __syncthreads();
    for (int i = tid; i < 128 * 16; i += 512) {
        int row = i >> 4, seg = i & 15;
        *(uint4*)(h + (size_t)(n0 + row) * FF + seg * 8) =
            *(const uint4*)(&sm.A[row][seg * 8]);
    }
}

__device__ __forceinline__ void edge_part512(SmemHE& sm, int blk,
                                             const float* __restrict__ dAp,
                                             const float* __restrict__ cAp,
                                             const bf16* __restrict__ fw1T_t,
                                             const float* __restrict__ fb1_t,
                                             const bf16* __restrict__ fw2T_t,
                                             const float* __restrict__ fb2_t,
                                             bf16* __restrict__ Wt) {
    int tid = threadIdx.x, e0 = blk * 128;
    if (tid < 128) {
        sm.dS[tid] = dAp[e0 + tid];
        sm.cS[tid] = cAp[e0 + tid];
        sm.b1S[tid] = fb1_t[tid];
        sm.b2S[tid] = fb2_t[tid];
    }
    stage_b512(&sm.B[0][0], fw1T_t, 0, 64, 64, tid);
    __syncthreads();
    const float width = 5.0f / 49.0f;
    const float coeff = -0.5f / (width * width);
    for (int idx = tid; idx < 128 * 32; idx += 512) {
        int i = idx >> 5, kp = (idx & 31) * 2;
        float d = sm.dS[i];
        float t0 = d - (float)kp * width;
        float t1 = d - (float)(kp + 1) * width;
        float v0 = (kp < GG)     ? __expf(coeff * t0 * t0) : 0.f;
        float v1 = (kp + 1 < GG) ? __expf(coeff * t1 * t1) : 0.f;
        *(unsigned int*)(&sm.A[i][kp]) = pk2(v0, v1);
    }
    __syncthreads();
    int wave = tid >> 6, lane = tid & 63, q = lane >> 4, ln = lane & 15;
    floatx4 acc[8];
#pragma unroll
    for (int j = 0; j < 8; j++) acc[j] = (floatx4){0.f, 0.f, 0.f, 0.f};
    // GEMM1: g(K=64) @ fw1 -> 2 n-chunks
    mfma64<4>(&sm.A[0][0], &sm.B[0][0], *(floatx4(*)[4])(&acc[0]), 0, wave, q, ln);
    __syncthreads();
    stage_b512(&sm.B[0][0], fw1T_t + 64 * 64, 0, 64, 64, tid);
    __syncthreads();
    mfma64<4>(&sm.A[0][0], &sm.B[0][0], *(floatx4(*)[4])(&acc[4]), 0, wave, q, ln);
    // u = ssp(.+b1) -> A (own-wave rows only)
#pragma unroll
    for (int cc = 0; cc < 8; cc++)
#pragma unroll
        for (int rg = 0; rg < 4; rg++) {
            int row = wave * 16 + q * 4 + rg;
            int col = (cc >> 2) * 64 + (cc & 3) * 16 + ln;
            sm.A[row][col] = f2b_fast(sspf(acc[cc][rg] + sm.b1S[col]));
        }
    __syncthreads();
    // GEMM2: u(K=128) @ fw2 -> 4 (n,k) chunks
    stage_b512(&sm.B[0][0], fw2T_t, 0, 64, 128, tid);
    __syncthreads();
#pragma unroll
    for (int j = 0; j < 8; j++) acc[j] = (floatx4){0.f, 0.f, 0.f, 0.f};
    mfma64<4>(&sm.A[0][0], &sm.B[0][0], *(floatx4(*)[4])(&acc[0]), 0, wave, q, ln);
    __syncthreads();
    stage_b512(&sm.B[0][0], fw2T_t + 64 * 128, 0, 64, 128, tid);
    __syncthreads();
    mfma64<4>(&sm.A[0][0], &sm.B[0][0], *(floatx4(*)[4])(&acc[4]), 0, wave, q, ln);
    __syncthreads();
    stage_b512(&sm.B[0][0], fw2T_t, 64, 64, 128, tid);
    __syncthreads();
    mfma64<4>(&sm.A[0][0], &sm.B[0][0], *(floatx4(*)[4])(&acc[0]), 64, wave, q, ln);
    __syncthreads();
    stage_b512(&sm.B[0][0], fw2T_t + 64 * 128, 64, 64, 128, tid);
    __syncthreads();
    mfma64<4>(&sm.A[0][0], &sm.B[0][0], *(floatx4(*)[4])(&acc[4]), 64, wave, q, ln);
    // W epilogue -> A (own rows), coalesced store
#pragma unroll
    for (int cc = 0; cc < 8; cc++)
#pragma unroll
        for (int rg = 0; rg < 4; rg++) {
            int row = wave * 16 + q * 4 + rg;
            int col = (cc >> 2) * 64 + (cc & 3) * 16 + ln;
            sm.A[row][col] = f2b_fast((acc[cc][rg] + sm.b2S[col]) * sm.cS[row]);
        }
    __syncthreads();
    for (int i = tid; i < 128 * 16; i += 512) {
        int row = i >> 4, seg = i & 15;
        *(uint4*)(Wt + (size_t)(e0 + row) * FF + seg * 8) =
            *(const uint4*)(&sm.A[row][seg * 8]);
    }
}

// merged h + edge-filter launch: 1:4 interleave, 512 threads
__global__ __launch_bounds__(512, 6) void k_he(const bf16* __restrict__ rb,
                                               const bf16* __restrict__ winT_t,
                                               bf16* __restrict__ h,
                                               const float* __restrict__ dAp,
                                               const float* __restrict__ cAp,
                                               const bf16* __restrict__ fw1T_t,
                                               const float* __restrict__ fb1_t,
                                               const bf16* __restrict__ fw2T_t,
                                               const float* __restrict__ fb2_t,
                                               bf16* __restrict__ Wt) {
    __shared__ SmemHE sm;
    int bi = blockIdx.x;
    if (bi % 5 == 0)
        h_part512(sm, bi / 5, rb, winT_t, h);
    else
        edge_part512(sm, bi - bi / 5 - 1, dAp, cAp, fw1T_t, fb1_t, fw2T_t, fb2_t, Wt);
}

// gather (paired rows, plain cached loads) + fused node MLP (round-11 verified)
__global__ __launch_bounds__(256, 5) void k_gather_node64(const int* __restrict__ baseA,
                                                          const int* __restrict__ a1s,
                                                          const int* __restrict__ ptr1,
                                                          const int* __restrict__ adj1,
                                                          const bf16* __restrict__ Wt,
                                                          const bf16* __restrict__ h,
                                                          const bf16* __restrict__ wout1T_t,
                                                          const float* __restrict__ bo1_t,
                                                          const bf16* __restrict__ wout2T_t,
                                                          const float* __restrict__ bo2_t,
                                                          bf16* __restrict__ rb) {
    __shared__ __align__(16) bf16 A[64][136];
    __shared__ __align__(16) bf16 B[64][72];
    __shared__ float b1S[128], b2S[128];
    int tid = threadIdx.x, n0 = blockIdx.x * 64;
    if (tid < 128) { b1S[tid] = bo1_t[tid]; b2S[tid] = bo2_t[tid]; }
    stage_b(&B[0][0], wout1T_t, 0, 64, 128, tid);  // overlap with gather
    int wave = tid >> 6, lane = tid & 63;
    int seg = lane & 15;   // cols [8*seg, 8*seg+8)
    int rg  = lane >> 4;   // slot-in-group 0..3
    for (int k = 0; k < 16; k += 2) {
        int rowA = wave * 16 + k;
        int atomA = n0 + rowA;
        int2 b01 = *(const int2*)(baseA + atomA);
        int b2v = baseA[atomA + 2];
        int2 p01 = *(const int2*)(ptr1 + atomA);
        int p2v = ptr1[atomA + 2];
        int sA0 = b01.x + rg, eA0v = b01.y;
        int sB0 = b01.y + rg, eB0v = b2v;
        int sA1 = p01.x + rg, eA1v = p01.y;
        int sB1 = p01.y + rg, eB1v = p2v;
        int oA = (sA0 < eA0v) ? a1s[sA0] : 0;
        int oB = (sB0 < eB0v) ? a1s[sB0] : 0;
        int2 eoA = (sA1 < eA1v) ? *(const int2*)(adj1 + 2 * sA1) : make_int2(0, 0);
        int2 eoB = (sB1 < eB1v) ? *(const int2*)(adj1 + 2 * sB1) : make_int2(0, 0);
        float acA[8], acB[8];
#pragma unroll
        for (int j = 0; j < 8; j++) { acA[j] = 0.f; acB[j] = 0.f; }
        while ((sA0 < eA0v) | (sA1 < eA1v) | (sB0 < eB0v) | (sB1 < eB1v)) {
            bool pA0 = sA0 < eA0v, pA1 = sA1 < eA1v;
            bool pB0 = sB0 < eB0v, pB1 = sB1 < eB1v;
            uint4 wvA0, hvA0, wvA1, hvA1, wvB0, hvB0, wvB1, hvB1;
            if (pA0) {
                wvA0 = *(const uint4*)(Wt + (size_t)sA0 * FF + seg * 8);
                hvA0 = *(const uint4*)(h + (size_t)oA * FF + seg * 8);
            }
            if (pA1) {
                wvA1 = *(const uint4*)(Wt + (size_t)eoA.x * FF + seg * 8);
                hvA1 = *(const uint4*)(h + (size_t)eoA.y * FF + seg * 8);
            }
            if (pB0) {
                wvB0 = *(const uint4*)(Wt + (size_t)sB0 * FF + seg * 8);
                hvB0 = *(const uint4*)(h + (size_t)oB * FF + seg * 8);
            }
            if (pB1) {
                wvB1 = *(const uint4*)(Wt + (size_t)eoB.x * FF + seg * 8);
                hvB1 = *(const uint4*)(h + (size_t)eoB.y * FF + seg * 8);
            }
            int sA0n = sA0 + 4, sA1n = sA1 + 4, sB0n = sB0 + 4, sB1n = sB1 + 4;
            int oAn = (sA0n < eA0v) ? a1s[sA0n] : 0;
            int oBn = (sB0n < eB0v) ? a1s[sB0n] : 0;
            int2 eoAn = (sA1n < eA1v) ? *(const int2*)(adj1 + 2 * sA1n) : make_int2(0, 0);
            int2 eoBn = (sB1n < eB1v) ? *(const int2*)(adj1 + 2 * sB1n) : make_int2(0, 0);
            if (pA0) fma8(acA, wvA0, hvA0);
            if (pA1) fma8(acA, wvA1, hvA1);
            if (pB0) fma8(acB, wvB0, hvB0);
            if (pB1) fma8(acB, wvB1, hvB1);
            sA0 = sA0n; sA1 = sA1n; sB0 = sB0n; sB1 = sB1n;
            oA = oAn; oB = oBn; eoA = eoAn; eoB = eoBn;
        }
#pragma unroll
        for (int j = 0; j < 8; j++) {
            float vA = acA[j], vB = acB[j];
            vA += __shfl_down(vA, 32); vB += __shfl_down(vB, 32);
            vA += __shfl_down(vA, 16); vB += __shfl_down(vB, 16);
            acA[j] = vA; acB[j] = vB;
        }
        if (rg == 0) {
            uint4 oU;
            oU.x = pk2(acA[0], acA[1]); oU.y = pk2(acA[2], acA[3]);
            oU.z = pk2(acA[4], acA[5]); oU.w = pk2(acA[6], acA[7]);
            *(uint4*)(&A[rowA][seg * 8]) = oU;
            oU.x = pk2(acB[0], acB[1]); oU.y = pk2(acB[2], acB[3]);
            oU.z = pk2(acB[4], acB[5]); oU.w = pk2(acB[6], acB[7]);
            *(uint4*)(&A[rowA + 1][seg * 8]) = oU;
        }
    }
    __syncthreads();
    int q = lane >> 4, ln = lane & 15;
    floatx4 acc[8];
#pragma unroll
    for (int j = 0; j < 8; j++) acc[j] = (floatx4){0.f, 0.f, 0.f, 0.f};
    mfma64<4>(&A[0][0], &B[0][0], *(floatx4(*)[4])(&acc[0]), 0, wave, q, ln);
    __syncthreads();
    stage_b(&B[0][0], wout1T_t + 64 * 128, 0, 64, 128, tid);
    __syncthreads();
    mfma64<4>(&A[0][0], &B[0][0], *(floatx4(*)[4])(&acc[4]), 0, wave, q, ln);
    __syncthreads();
    stage_b(&B[0][0], wout1T_t, 64, 64, 128, tid);
    __syncthreads();
    mfma64<4>(&A[0][0], &B[0][0], *(floatx4(*)[4])(&acc[0]), 64, wave, q, ln);
    __syncthreads();
    stage_b(&B[0][0], wout1T_t + 64 * 128, 64, 64, 128, tid);
    __syncthreads();
    mfma64<4>(&A[0][0], &B[0][0], *(floatx4(*)[4])(&acc[4]), 64, wave, q, ln);
#pragma unroll
    for (int cc = 0; cc < 8; cc++)
#pragma unroll
        for (int rgi = 0; rgi < 4; rgi++) {
            int row = wave * 16 + q * 4 + rgi;
            int col = (cc >> 2) * 64 + (cc & 3) * 16 + ln;
            A[row][col] = f2b_fast(sspf(acc[cc][rgi] + b1S[col]));
        }
    __syncthreads();
    stage_b(&B[0][0], wout2T_t, 0, 64, 128, tid);
    __syncthreads();
#pragma unroll
    for (int j = 0; j < 8; j++) acc[j] = (floatx4){0.f, 0.f, 0.f, 0.f};
    mfma64<4>(&A[0][0], &B[0][0], *(floatx4(*)[4])(&acc[0]), 0, wave, q, ln);
    __syncthreads();
    stage_b(&B[0][0], wout2T_t + 64 * 128, 0, 64, 128, tid);
    __syncthreads();
    mfma64<4>(&A[0][0], &B[0][0], *(floatx4(*)[4])(&acc[4]), 0, wave, q, ln);
    __syncthreads();
    stage_b(&B[0][0], wout2T_t, 64, 64, 128, tid);
    __syncthreads();
    mfma64<4>(&A[0][0], &B[0][0], *(floatx4(*)[4])(&acc[0]), 64, wave, q, ln);
    __syncthreads();
    stage_b(&B[0][0], wout2T_t + 64 * 128, 64, 64, 128, tid);
    __syncthreads();
    mfma64<4>(&A[0][0], &B[0][0], *(floatx4(*)[4])(&acc[4]), 64, wave, q, ln);
#pragma unroll
    for (int cc = 0; cc < 8; cc++)
#pragma unroll
        for (int rgi = 0; rgi < 4; rgi++) {
            int row = wave * 16 + q * 4 + rgi;
            int col = (cc >> 2) * 64 + (cc & 3) * 16 + ln;
            size_t off = (size_t)(n0 + row) * DD + col;
            rb[off] = f2b_fast(b2f(rb[off]) + acc[cc][rgi] + b2S[col]);
        }
}

// ---------------------------------------------------------------------------
// FALLBACK (verified structure, bf16 r)
// ---------------------------------------------------------------------------
__global__ __launch_bounds__(256) void k_h(const bf16* __restrict__ rb,
                                           const bf16* __restrict__ winT_t,
                                           bf16* __restrict__ h,
                                           float* __restrict__ y) {
    __shared__ __align__(16) bf16 A[128][136];
    __shared__ __align__(16) bf16 B[128][72];
    int tid = threadIdx.x, n0 = blockIdx.x * 128;
    for (int i = tid; i < 128 * 16; i += 256) {
        int row = i >> 4, seg = i & 15;
        *(uint4*)(&A[row][seg * 8]) =
            *(const uint4*)(rb + (size_t)(n0 + row) * DD + seg * 8);
        *(float4*)(y + (size_t)(n0 + row) * FF + seg * 8) = (float4){0.f, 0.f, 0.f, 0.f};
        *(float4*)(y + (size_t)(n0 + row) * FF + seg * 8 + 4) = (float4){0.f, 0.f, 0.f, 0.f};
    }
    stage_b(&B[0][0], winT_t, 0, 128, 128, tid);
    __syncthreads();
    int wave = tid >> 6, lane = tid & 63, q = lane >> 4, ln = lane & 15;
    floatx4 acc[2][8];
#pragma unroll
    for (int i = 0; i < 2; i++)
#pragma unroll
        for (int j = 0; j < 8; j++) acc[i][j] = (floatx4){0.f, 0.f, 0.f, 0.f};
    mfma_half<8>(&A[0][0], &B[0][0], acc, 0, wave, q, ln);
    __syncthreads();
    stage_b(&B[0][0], winT_t, 64, 128, 128, tid);
    __syncthreads();
    mfma_half<8>(&A[0][0], &B[0][0], acc, 64, wave, q, ln);
#pragma unroll
    for (int rt = 0; rt < 2; rt++)
#pragma unroll
        for (int ct = 0; ct < 8; ct++)
#pragma unroll
            for (int rg = 0; rg < 4; rg++) {
                int row = wave * 32 + rt * 16 + q * 4 + rg, col = ct * 16 + ln;
                h[(size_t)(n0 + row) * FF + col] = f2b(acc[rt][ct][rg]);
            }
}

__global__ __launch_bounds__(256) void k_edge(const float* __restrict__ dArr,
                                              const float* __restrict__ cArr,
                                              const int* __restrict__ a,
                                              const bf16* __restrict__ fw1T_t,
                                              const float* __restrict__ fb1_t,
                                              const bf16* __restrict__ fw2T_t,
                                              const float* __restrict__ fb2_t,
                                              const bf16* __restrict__ h,
                                              float* __restrict__ y) {
    __shared__ __align__(16) bf16 A[128][136];
    __shared__ __align__(16) bf16 B[128][72];
    __shared__ float dS[128], cS[128], b1S[128], b2S[128];
    __shared__ int a0S[128], a1S[128];
    int tid = threadIdx.x, e0 = blockIdx.x * 128;
    if (tid < 128) {
        int e = e0 + tid;
        dS[tid] = dArr[e]; cS[tid] = cArr[e];
        a0S[tid] = a[2 * e]; a1S[tid] = a[2 * e + 1];
        b1S[tid] = fb1_t[tid]; b2S[tid] = fb2_t[tid];
    }
    stage_b(&B[0][0], fw1T_t, 0, 128, 64, tid);
    __syncthreads();
    const float width = 5.0f / 49.0f;
    const float coeff = -0.5f / (width * width);
    for (int idx = tid; idx < 128 * 64; idx += 256) {
        int i = idx >> 6, k = idx & 63;
        float v = 0.f;
        if (k < GG) { float t = dS[i] - (float)k * width; v = __expf(coeff * t * t); }
        A[i][k] = f2b(v);
    }
    __syncthreads();
    int wave = tid >> 6, lane = tid & 63, q = lane >> 4, ln = lane & 15;
    floatx4 acc[2][8];
#pragma unroll
    for (int i = 0; i < 2; i++)
#pragma unroll
        for (int j = 0; j < 8; j++) acc[i][j] = (floatx4){0.f, 0.f, 0.f, 0.f};
    mfma_half<8>(&A[0][0], &B[0][0], acc, 0, wave, q, ln);
#pragma unroll
    for (int rt = 0; rt < 2; rt++)
#pragma unroll
        for (int ct = 0; ct < 8; ct++)
#pragma unroll
            for (int rg = 0; rg < 4; rg++) {
                int row = wave * 32 + rt * 16 + q * 4 + rg, col = ct * 16 + ln;
                A[row][col] = f2b(sspf(acc[rt][ct][rg] + b1S[col]));
            }
    __syncthreads();
    stage_b(&B[0][0], fw2T_t, 0, 128, 128, tid);
    __syncthreads();
#pragma unroll
    for (int i = 0; i < 2; i++)
#pragma unroll
        for (int j = 0; j < 8; j++) acc[i][j] = (floatx4){0.f, 0.f, 0.f, 0.f};
    mfma_half<8>(&A[0][0], &B[0][0], acc, 0, wave, q, ln);
    __syncthreads();
    stage_b(&B[0][0], fw2T_t, 64, 128, 128, tid);
    __syncthreads();
    mfma_half<8>(&A[0][0], &B[0][0], acc, 64, wave, q, ln);
#pragma unroll
    for (int rt = 0; rt < 2; rt++)
#pragma unroll
        for (int ct = 0; ct < 8; ct++)
#pragma unroll
            for (int rg = 0; rg < 4; rg++) {
                int row = wave * 32 + rt * 16 + q * 4 + rg, col = ct * 16 + ln;
                float w = (acc[rt][ct][rg] + b2S[col]) * cS[row];
                int A0 = a0S[row], A1 = a1S[row];
                float h0 = b2f(h[A0 * FF + col]);
                float h1 = b2f(h[A1 * FF + col]);
                atomicAdd(&y[A0 * FF + col], h1 * w);
                atomicAdd(&y[A1 * FF + col], h0 * w);
            }
}

__global__ __launch_bounds__(256) void k_node(const float* __restrict__ y,
                                              const bf16* __restrict__ wout1T_t,
                                              const float* __restrict__ bo1_t,
                                              const bf16* __restrict__ wout2T_t,
                                              const float* __restrict__ bo2_t,
                                              bf16* __restrict__ rb) {
    __shared__ __align__(16) bf16 A[128][136];
    __shared__ __align__(16) bf16 B[128][72];
    __shared__ float b1S[128], b2S[128];
    int tid = threadIdx.x, n0 = blockIdx.x * 128;
    if (tid < 128) { b1S[tid] = bo1_t[tid]; b2S[tid] = bo2_t[tid]; }
    for (int idx = tid; idx < 128 * 128; idx += 256) {
        int row = idx >> 7, col = idx & 127;
        A[row][col] = f2b(y[(size_t)(n0 + row) * FF + col]);
    }
    stage_b(&B[0][0], wout1T_t, 0, 128, 128, tid);
    __syncthreads();
    int wave = tid >> 6, lane = tid & 63, q = lane >> 4, ln = lane & 15;
    floatx4 acc[2][8];
#pragma unroll
    for (int i = 0; i < 2; i++)
#pragma unroll
        for (int j = 0; j < 8; j++) acc[i][j] = (floatx4){0.f, 0.f, 0.f, 0.f};
    mfma_half<8>(&A[0][0], &B[0][0], acc, 0, wave, q, ln);
    __syncthreads();
    stage_b(&B[0][0], wout1T_t, 64, 128, 128, tid);
    __syncthreads();
    mfma_half<8>(&A[0][0], &B[0][0], acc, 64, wave, q, ln);
#pragma unroll
    for (int rt = 0; rt < 2; rt++)
#pragma unroll
        for (int ct = 0; ct < 8; ct++)
#pragma unroll
            for (int rg = 0; rg < 4; rg++) {
                int row = wave * 32 + rt * 16 + q * 4 + rg, col = ct * 16 + ln;
                A[row][col] = f2b(sspf(acc[rt][ct][rg] + b1S[col]));
            }
    __syncthreads();
    stage_b(&B[0][0], wout2T_t, 0, 128, 128, tid);
    __syncthreads();
#pragma unroll
    for (int i = 0; i < 2; i++)
#pragma unroll
        for (int j = 0; j < 8; j++) acc[i][j] = (floatx4){0.f, 0.f, 0.f, 0.f};
    mfma_half<8>(&A[0][0], &B[0][0], acc, 0, wave, q, ln);
    __syncthreads();
    stage_b(&B[0][0], wout2T_t, 64, 128, 128, tid);
    __syncthreads();
    mfma_half<8>(&A[0][0], &B[0][0], acc, 64, wave, q, ln);
#pragma unroll
    for (int rt = 0; rt < 2; rt++)
#pragma unroll
        for (int ct = 0; ct < 8; ct++)
#pragma unroll
            for (int rg = 0; rg < 4; rg++) {
                int row = wave * 32 + rt * 16 + q * 4 + rg, col = ct * 16 + ln;
                size_t off = (size_t)(n0 + row) * DD + col;
                rb[off] = f2b_fast(b2f(rb[off]) + acc[rt][ct][rg] + b2S[col]);
            }
}

// ---------------------------------------------------------------------------
__global__ __launch_bounds__(256) void k_head(const bf16* __restrict__ rb,
                                              const bf16* __restrict__ wa1T,
                                              const float* __restrict__ ba1,
                                              const float* __restrict__ wa2,
                                              const float* __restrict__ ba2,
                                              const int* __restrict__ mol,
                                              float* __restrict__ molE) {
    __shared__ __align__(16) bf16 A[128][136];
    __shared__ __align__(16) bf16 B[64][72];
    __shared__ __align__(16) bf16 U[128][72];
    __shared__ float wa2S[64], ba1S[64];
    int tid = threadIdx.x, n0 = blockIdx.x * 128;
    if (tid < 64) { wa2S[tid] = wa2[tid]; ba1S[tid] = ba1[tid]; }
    for (int i = tid; i < 128 * 16; i += 256) {
        int row = i >> 4, seg = i & 15;
        *(uint4*)(&A[row][seg * 8]) =
            *(const uint4*)(rb + (size_t)(n0 + row) * DD + seg * 8);
    }
    stage_b(&B[0][0], wa1T, 0, 64, 128, tid);
    __syncthreads();
    int wave = tid >> 6, lane = tid & 63, q = lane >> 4, ln = lane & 15;
    floatx4 acc[2][4];
#pragma unroll
    for (int i = 0; i < 2; i++)
#pragma unroll
        for (int j = 0; j < 4; j++) acc[i][j] = (floatx4){0.f, 0.f, 0.f, 0.f};
    mfma_half<4>(&A[0][0], &B[0][0], acc, 0, wave, q, ln);
    __syncthreads();
    stage_b(&B[0][0], wa1T, 64, 64, 128, tid);
    __syncthreads();
    mfma_half<4>(&A[0][0], &B[0][0], acc, 64, wave, q, ln);
#pragma unroll
    for (int rt = 0; rt < 2; rt++)
#pragma unroll
        for (int ct = 0; ct < 4; ct++)
#pragma unroll
            for (int rg = 0; rg < 4; rg++) {
                int row = wave * 32 + rt * 16 + q * 4 + rg, col = ct * 16 + ln;
                U[row][col] = f2b_fast(acc[rt][ct][rg] + ba1S[col]);
            }
    __syncthreads();
    if (tid < 128) {
        float s = ba2[0];
#pragma unroll
        for (int j = 0; j < 64; j++) s += sspf(b2f(U[tid][j])) * wa2S[j];
        atomicAdd(&molE[mol[n0 + tid]], s);
    }
}

// ---------------------------------------------------------------------------
extern "C" void kernel_launch(void* const* d_in, const int* in_sizes, int n_in,
                              void* d_out, int out_size, void* d_ws, size_t ws_size,
                              hipStream_t stream) {
    const float* xyz   = (const float*)d_in[0];
    const float* emb   = (const float*)d_in[1];
    const float* fw1   = (const float*)d_in[2];
    const float* fb1   = (const float*)d_in[3];
    const float* fw2   = (const float*)d_in[4];
    const float* fb2   = (const float*)d_in[5];
    const float* win   = (const float*)d_in[6];
    const float* wout1 = (const float*)d_in[7];
    const float* bout1 = (const float*)d_in[8];
    const float* wout2 = (const float*)d_in[9];
    const float* bout2 = (const float*)d_in[10];
    const float* wa1   = (const float*)d_in[11];
    const float* ba1   = (const float*)d_in[12];
    const float* wa2   = (const float*)d_in[13];
    const float* ba2   = (const float*)d_in[14];
    const int*  z     = (const int*)d_in[15];
    const int*  a     = (const int*)d_in[16];
    const int*  mol   = (const int*)d_in[17];

    float* molE = (float*)d_out;   // accumulate per-mol energy directly in d_out

    char* ws = (char*)d_ws;
    bf16*  rb   = (bf16*) ws; ws += (size_t)N_ATOMS * DD * 2;     //  33,554,432
    bf16*  h    = (bf16*) ws; ws += (size_t)N_ATOMS * FF * 2;     //  33,554,432
    float* dAp  = (float*)ws; ws += (size_t)N_EDGES * 4;          //   2,097,152
    float* cAp  = (float*)ws; ws += (size_t)N_EDGES * 4;          //   2,097,152
    bf16*  fw1T   = (bf16*)ws; ws += 3 * 128 * 64 * 2;
    bf16*  fw2T   = (bf16*)ws; ws += 3 * 128 * 128 * 2;
    bf16*  winT   = (bf16*)ws; ws += 3 * 128 * 128 * 2;
    bf16*  wout1T = (bf16*)ws; ws += 3 * 128 * 128 * 2;
    bf16*  wout2T = (bf16*)ws; ws += 3 * 128 * 128 * 2;
    bf16*  wa1T   = (bf16*)ws; ws += 64 * 128 * 2;
    char*  csr_base = ws;                                          // fallback y aliases here
    int*   baseA   = (int*)ws; ws += 524320;                      // N_ATOMS+1, padded
    int*   ptr1    = (int*)ws; ws += 524320;
    int*   cursorA = (int*)ws; ws += (size_t)N_ATOMS * 4;
    int*   cursor1 = (int*)ws; ws += (size_t)N_ATOMS * 4;
    int*   a1s     = (int*)ws; ws += (size_t)N_EDGES * 4;         //   2,097,152
    int*   adj1    = (int*)ws; ws += (size_t)2 * N_EDGES * 4;     //   4,194,304
    int*   bsumA   = (int*)ws; ws += 1024;
    int*   bsum1   = (int*)ws; ws += 1024;
    bf16*  Wt      = (bf16*)ws; ws += (size_t)N_EDGES * FF * 2;   // 134,217,728
    size_t need = (size_t)(ws - (char*)d_ws);                     // ~214 MB

    k_initwt<<<N_ATOMS * 16 / 256 + 896, 256, 0, stream>>>(
        emb, z, rb, fw1, fw2, win, wout1, wout2, wa1,
        fw1T, fw2T, winT, wout1T, wout2T, wa1T);

    if (ws_size >= need) {
        k_zero2<<<2 * N_ATOMS / 256, 256, 0, stream>>>(cursorA, cursor1);
        k_count2<<<N_EDGES / 256, 256, 0, stream>>>(a, cursorA, cursor1, molE);
        k_scan1j<<<512, 256, 0, stream>>>(cursorA, cursor1, bsumA, bsum1);
        k_scan2j<<<1, 256, 0, stream>>>(bsumA, bsum1, baseA, ptr1);
        k_scan3j<<<512, 256, 0, stream>>>(cursorA, cursor1, bsumA, bsum1, baseA, ptr1);
        k_permA<<<N_EDGES / 256, 256, 0, stream>>>(xyz, a, cursorA, cursor1,
                                                   dAp, cAp, a1s, adj1);
        for (int t = 0; t < TT; t++) {
            k_he<<<N_ATOMS / 128 + N_EDGES / 128, 512, 0, stream>>>(
                rb, winT + t * 16384, h, dAp, cAp,
                fw1T + t * 8192, fb1 + t * FF,
                fw2T + t * 16384, fb2 + t * FF, Wt);
            k_gather_node64<<<N_ATOMS / 64, 256, 0, stream>>>(
                baseA, a1s, ptr1, adj1, Wt, h,
                wout1T + t * 16384, bout1 + t * DD,
                wout2T + t * 16384, bout2 + t * DD, rb);
        }
    } else {
        // fallback: verified atomic-scatter path (y aliases CSR region)
        float* y = (float*)csr_base;
        k_dist<<<N_EDGES / 256, 256, 0, stream>>>(xyz, a, dAp, cAp, molE);
        for (int t = 0; t < TT; t++) {
            k_h<<<N_ATOMS / 128, 256, 0, stream>>>(rb, winT + t * 16384, h, y);
            k_edge<<<N_EDGES / 128, 256, 0, stream>>>(dAp, cAp, a,
                                                      fw1T + t * 8192, fb1 + t * FF,
                                                      fw2T + t * 16384, fb2 + t * FF, h, y);
            k_node<<<N_ATOMS / 128, 256, 0, stream>>>(y, wout1T + t * 16384, bout1 + t * DD,
                                                      wout2T + t * 16384, bout2 + t * DD, rb);
        }
    }
    k_head<<<N_ATOMS / 128, 256, 0, stream>>>(rb, wa1T, ba1, wa2, ba2, mol, molE);
}